// Round 10
// baseline (511.640 us; speedup 1.0000x reference)
//
#include <hip/hip_runtime.h>
#include <math.h>

typedef _Float16 half4 __attribute__((ext_vector_type(4)));
typedef _Float16 half8 __attribute__((ext_vector_type(8)));
typedef float f32x4 __attribute__((ext_vector_type(4)));

#define GLD16(gptr, lptr)                                                     \
    __builtin_amdgcn_global_load_lds(                                         \
        (const __attribute__((address_space(1))) unsigned int*)(gptr),        \
        (__attribute__((address_space(3))) unsigned int*)(lptr), 16, 0, 0)

#define WAIT_VM(N) asm volatile("s_waitcnt vmcnt(" #N ")" ::: "memory")
#define WAIT_LGKM0() asm volatile("s_waitcnt lgkmcnt(0)" ::: "memory")
#define BARRIER()  __builtin_amdgcn_s_barrier()
#define SCHED_FENCE() __builtin_amdgcn_sched_barrier(0)

namespace {

constexpr int Bb = 4;
constexpr int Tt = 2048;
constexpr int Dd = 1024;
constexpr int BT = Bb * Tt;   // 8192
constexpr int NCH = 16;       // stats chunks = 128-row tiles

__device__ inline _Float16 f2h(float f) { return (_Float16)f; }

// ---------------------------------------------------------------------------
// FUSED converts: X -> Xhi/Xlo ; Wq,Wk -> hi/lo ; Wv -> WvT hi.
// ---------------------------------------------------------------------------
__global__ __launch_bounds__(256) void convert_all_kernel(
    const float* __restrict__ X,  const float* __restrict__ Wq,
    const float* __restrict__ Wk, const float* __restrict__ Wv,
    _Float16* __restrict__ Xhi, _Float16* __restrict__ Xlo,
    _Float16* __restrict__ Wqh, _Float16* __restrict__ Wql,
    _Float16* __restrict__ Wkh, _Float16* __restrict__ Wkl,
    _Float16* __restrict__ WvTh)
{
    __shared__ float tile[64][65];
    const int f = blockIdx.x;
    if (f < 8192) {
        const int idx = f * 1024 + threadIdx.x * 4;
        const float4 v = *(const float4*)(X + idx);
        const float a[4] = {v.x, v.y, v.z, v.w};
        half4 h, l;
#pragma unroll
        for (int i = 0; i < 4; ++i) {
            h[i] = f2h(a[i]);
            l[i] = f2h(a[i] - (float)h[i]);
        }
        *(half4*)(Xhi + idx) = h;
        *(half4*)(Xlo + idx) = l;
    } else if (f < 10240) {
        const int g = f - 8192;
        const int mat = g >> 10;
        const float* W = mat ? Wk : Wq;
        _Float16* Hh = mat ? Wkh : Wqh;
        _Float16* Ll = mat ? Wkl : Wql;
        const int idx = (g & 1023) * 1024 + threadIdx.x * 4;
        const float4 v = *(const float4*)(W + idx);
        const float a[4] = {v.x, v.y, v.z, v.w};
        half4 h, l;
#pragma unroll
        for (int i = 0; i < 4; ++i) {
            h[i] = f2h(a[i]);
            l[i] = f2h(a[i] - (float)h[i]);
        }
        *(half4*)(Hh + idx) = h;
        *(half4*)(Ll + idx) = l;
    } else {
        const int g = f - 10240;
        const int n0 = (g & 15) * 64, k0 = (g >> 4) * 64;
        const int tx = threadIdx.x & 63, ty = threadIdx.x >> 6;
#pragma unroll
        for (int i = 0; i < 16; ++i)
            tile[ty + i * 4][tx] = Wv[(size_t)(k0 + ty + i * 4) * Dd + n0 + tx];
        __syncthreads();
#pragma unroll
        for (int i = 0; i < 16; ++i) {
            const float v = tile[tx][ty + i * 4];
            WvTh[(size_t)(n0 + ty + i * 4) * Dd + k0 + tx] = f2h(v);
        }
    }
}

// ---------------------------------------------------------------------------
// GT[s][r] = sum_a Wk[s][a] * Wq[r][a]   (counted-vmcnt pipeline)
// ---------------------------------------------------------------------------
__global__ __launch_bounds__(256) void gt_kernel(
    const _Float16* __restrict__ Wkh, const _Float16* __restrict__ Wkl,
    const _Float16* __restrict__ Wqh, const _Float16* __restrict__ Wql,
    _Float16* __restrict__ GTh, _Float16* __restrict__ GTl)
{
    __shared__ _Float16 Ahl[2][2][4][512];
    __shared__ _Float16 Bhl[2][2][4][512];

    const int n0 = blockIdx.x * 64;
    const int m0 = blockIdx.y * 64;
    const int tid = threadIdx.x;
    const int w = tid >> 6, lane = tid & 63;
    const int lr = lane & 15, lq = lane >> 4;
    const int wi = (w >> 1) * 2, wj = (w & 1) * 2;

    f32x4 acc[2][2];
#pragma unroll
    for (int i = 0; i < 2; ++i)
#pragma unroll
        for (int j = 0; j < 2; ++j)
#pragma unroll
            for (int c = 0; c < 4; ++c) acc[i][j][c] = 0.f;

    auto stage = [&](int bf, int kk) {
        const int s = w;
        const size_t ar = (size_t)(m0 + s * 16 + lr) * Dd + kk + lq * 8;
        const size_t br = (size_t)(n0 + s * 16 + lr) * Dd + kk + lq * 8;
        GLD16(Wkh + ar, &Ahl[bf][0][s][0]);
        GLD16(Wkl + ar, &Ahl[bf][1][s][0]);
        GLD16(Wqh + br, &Bhl[bf][0][s][0]);
        GLD16(Wql + br, &Bhl[bf][1][s][0]);
    };

    stage(0, 0);
    int ib = 0;
    for (int step = 0; step < 32; ++step, ib ^= 1) {
        if (step < 31) {
            stage(ib ^ 1, (step + 1) << 5);
            WAIT_VM(4);
        } else {
            WAIT_VM(0);
        }
        BARRIER();
        SCHED_FENCE();
        half8 ah[2], al[2], bh[2], bl[2];
#pragma unroll
        for (int i = 0; i < 2; ++i) {
            ah[i] = *(const half8*)&Ahl[ib][0][wi + i][lane * 8];
            al[i] = *(const half8*)&Ahl[ib][1][wi + i][lane * 8];
        }
#pragma unroll
        for (int j = 0; j < 2; ++j) {
            bh[j] = *(const half8*)&Bhl[ib][0][wj + j][lane * 8];
            bl[j] = *(const half8*)&Bhl[ib][1][wj + j][lane * 8];
        }
#pragma unroll
        for (int i = 0; i < 2; ++i)
#pragma unroll
            for (int j = 0; j < 2; ++j) {
                acc[i][j] = __builtin_amdgcn_mfma_f32_16x16x32_f16(ah[i], bh[j], acc[i][j], 0, 0, 0);
                acc[i][j] = __builtin_amdgcn_mfma_f32_16x16x32_f16(ah[i], bl[j], acc[i][j], 0, 0, 0);
                acc[i][j] = __builtin_amdgcn_mfma_f32_16x16x32_f16(al[i], bh[j], acc[i][j], 0, 0, 0);
            }
        BARRIER();
    }

#pragma unroll
    for (int i = 0; i < 2; ++i)
#pragma unroll
        for (int r = 0; r < 4; ++r) {
            const int row = m0 + (wi + i) * 16 + lq * 4 + r;
#pragma unroll
            for (int j = 0; j < 2; ++j) {
                const int col = n0 + (wj + j) * 16 + lr;
                const float v = acc[i][j][r];
                const _Float16 h = f2h(v);
                GTh[(size_t)row * Dd + col] = h;
                GTl[(size_t)row * Dd + col] = f2h(v - (float)h);
            }
        }
}

// ---------------------------------------------------------------------------
// FUSED  T = X*G (3-product hi/lo)  +  V = X*Wv (single product).
// ROLE-BALANCED mapping (round-8, measured win). v-role epilogue writes Vt.
// ---------------------------------------------------------------------------
__global__ __launch_bounds__(256, 2) void tv_kernel(
    const _Float16* __restrict__ Xhi, const _Float16* __restrict__ Xlo,
    const _Float16* __restrict__ GTh, const _Float16* __restrict__ GTl,
    const _Float16* __restrict__ WvTh,
    _Float16* __restrict__ Thi, _Float16* __restrict__ Tlo,
    _Float16* __restrict__ Vt)
{
    __shared__ _Float16 smem[32768];   // 64 KB: staging dbuf; v-role epilogue scratch
    auto A_ = [&](int bf, int hl, int s) -> _Float16* {
        return smem + ((bf * 2 + hl) * 8 + s) * 512;
    };
    auto B_ = [&](int bf, int hl, int s) -> _Float16* {
        return smem + 16384 + ((bf * 2 + hl) * 8 + s) * 512;
    };

    const int f   = blockIdx.x;           // 0..1023
    const int xcd = f & 7;
    const int c   = (f >> 3) & 31;        // CU within XCD (assumed)
    const int p   = f >> 8;               // resident slot (assumed)
    const int mb  = xcd * 8 + (c & 7);    // m-panel 0..63
    const int sub = p * 4 + (c >> 3);     // 0..15; p<2 -> t-role
    const int m0 = mb * 128;
    const int n0 = (sub & 7) * 128;

    const int tid = threadIdx.x;
    const int w = tid >> 6, lane = tid & 63;
    const int lr = lane & 15, lq = lane >> 4;
    const int wr = (w >> 1) * 4, wc = (w & 1) * 4;

    f32x4 acc[4][4];
#pragma unroll
    for (int i = 0; i < 4; ++i)
#pragma unroll
        for (int j = 0; j < 4; ++j)
#pragma unroll
            for (int c2 = 0; c2 < 4; ++c2) acc[i][j][c2] = 0.f;

    if (sub < 8) {
        // ----- t-role: 3-product hi/lo -----
        auto stage = [&](int bf, int kk) {
#pragma unroll
            for (int s2 = 0; s2 < 2; ++s2) {
                const int s = w * 2 + s2;
                const size_t ar = (size_t)(m0 + s * 16 + lr) * Dd + kk + lq * 8;
                const size_t br = (size_t)(n0 + s * 16 + lr) * Dd + kk + lq * 8;
                GLD16(Xhi + ar, A_(bf, 0, s));
                GLD16(Xlo + ar, A_(bf, 1, s));
                GLD16(GTh + br, B_(bf, 0, s));
                GLD16(GTl + br, B_(bf, 1, s));
            }
        };
        stage(0, 0);
        int ib = 0;
        for (int step = 0; step < 32; ++step, ib ^= 1) {
            if (step < 31) {
                stage(ib ^ 1, (step + 1) << 5);
                WAIT_VM(8);
            } else {
                WAIT_VM(0);
            }
            BARRIER();
            SCHED_FENCE();
            half8 ah[4], al[4], bh[4], bl[4];
#pragma unroll
            for (int i = 0; i < 4; ++i) {
                ah[i] = *(const half8*)(A_(ib, 0, wr + i) + lane * 8);
                al[i] = *(const half8*)(A_(ib, 1, wr + i) + lane * 8);
            }
#pragma unroll
            for (int j = 0; j < 4; ++j) {
                bh[j] = *(const half8*)(B_(ib, 0, wc + j) + lane * 8);
                bl[j] = *(const half8*)(B_(ib, 1, wc + j) + lane * 8);
            }
#pragma unroll
            for (int i = 0; i < 4; ++i)
#pragma unroll
                for (int j = 0; j < 4; ++j) {
                    acc[i][j] = __builtin_amdgcn_mfma_f32_16x16x32_f16(ah[i], bh[j], acc[i][j], 0, 0, 0);
                    acc[i][j] = __builtin_amdgcn_mfma_f32_16x16x32_f16(ah[i], bl[j], acc[i][j], 0, 0, 0);
                    acc[i][j] = __builtin_amdgcn_mfma_f32_16x16x32_f16(al[i], bh[j], acc[i][j], 0, 0, 0);
                }
            BARRIER();
        }
#pragma unroll
        for (int i = 0; i < 4; ++i)
#pragma unroll
            for (int r = 0; r < 4; ++r) {
                const int row = m0 + (wr + i) * 16 + lq * 4 + r;
#pragma unroll
                for (int j = 0; j < 4; ++j) {
                    const int col = n0 + (wc + j) * 16 + lr;
                    const float v = acc[i][j][r];
                    const _Float16 h = f2h(v);
                    Thi[(size_t)row * Dd + col] = h;
                    Tlo[(size_t)row * Dd + col] = f2h(v - (float)h);
                }
            }
    } else {
        // ----- v-role: single product -----
        auto stage = [&](int bf, int kk) {
#pragma unroll
            for (int s2 = 0; s2 < 2; ++s2) {
                const int s = w * 2 + s2;
                GLD16(Xhi + (size_t)(m0 + s * 16 + lr) * Dd + kk + lq * 8, A_(bf, 0, s));
                GLD16(WvTh + (size_t)(n0 + s * 16 + lr) * Dd + kk + lq * 8, B_(bf, 0, s));
            }
        };
        stage(0, 0);
        int ib = 0;
        for (int step = 0; step < 32; ++step, ib ^= 1) {
            if (step < 31) {
                stage(ib ^ 1, (step + 1) << 5);
                WAIT_VM(4);
            } else {
                WAIT_VM(0);
            }
            BARRIER();
            SCHED_FENCE();
            half8 a[4], b2[4];
#pragma unroll
            for (int i = 0; i < 4; ++i) a[i] = *(const half8*)(A_(ib, 0, wr + i) + lane * 8);
#pragma unroll
            for (int j = 0; j < 4; ++j) b2[j] = *(const half8*)(B_(ib, 0, wc + j) + lane * 8);
#pragma unroll
            for (int i = 0; i < 4; ++i)
#pragma unroll
                for (int j = 0; j < 4; ++j)
                    acc[i][j] = __builtin_amdgcn_mfma_f32_16x16x32_f16(a[i], b2[j], acc[i][j], 0, 0, 0);
            BARRIER();
        }
        // ----- epilogue: write Vt[b][d][t] (pure transpose) via LDS -----
        __syncthreads();
#pragma unroll
        for (int i = 0; i < 4; ++i)
#pragma unroll
            for (int r2 = 0; r2 < 4; ++r2) {
                const int rloc = (wr + i) * 16 + lq * 4 + r2;   // local t-row
#pragma unroll
                for (int j = 0; j < 4; ++j) {
                    const int cloc = (wc + j) * 16 + lr;        // local d-col
                    smem[cloc * 136 + rloc] = f2h(acc[i][j][r2]);
                }
            }
        __syncthreads();
        const int b2i = m0 >> 11;            // batch (panels never straddle)
        const int t0  = m0 & 2047;
        const int dloc = tid >> 1, tl = (tid & 1) * 64;
        _Float16* vp = Vt + (size_t)b2i * Dd * Tt + (size_t)(n0 + dloc) * Tt + t0 + tl;
#pragma unroll
        for (int e = 0; e < 8; ++e)
            *(half8*)(vp + e * 8) = *(const half8*)&smem[dloc * 136 + tl + e * 8];
    }
}

// ---------------------------------------------------------------------------
// scores + FUSED column stats + P' write.  P' = f16(exp(Sf - chunkmax)).
// A (T hi/lo) via GLD16 LDS dbuf (32 KB).  B (X hi/lo) via DEPTH-2 register
// prefetch (named sets Be/Bo, 2-step unroll) -- context pattern.  Per step:
// issue stageA(step+1)[4] after prior step's loadB(step+1)[8] -> WAIT_VM(12)
// retires exactly {A(step), B(step)} keeping {B(step+1), A(step+1)} flying.
// LDS read traffic halved vs round-8; B latency hidden (round-9 fix).
// ---------------------------------------------------------------------------
__global__ __launch_bounds__(256, 3) void scores_mfma_kernel(
    const _Float16* __restrict__ Thi, const _Float16* __restrict__ Tlo,
    const _Float16* __restrict__ Xhi, const _Float16* __restrict__ Xlo,
    _Float16* __restrict__ Pp, float* __restrict__ Pm, float* __restrict__ Pl)
{
    const int f  = blockIdx.x;                // 0..543
    const int fp = (f & 7) * 68 + (f >> 3);   // chunked bijective
    const int b = fp / 136;
    const int t = fp - b * 136;
    int byi = (int)((sqrtf(8.f * t + 1.f) - 1.f) * 0.5f);
    if ((byi + 1) * (byi + 2) / 2 <= t) ++byi;
    if (byi * (byi + 1) / 2 > t) --byi;
    const int bxi = t - byi * (byi + 1) / 2;
    const int j0 = bxi * 128, q0 = byi * 128;
    _Float16* Pb = Pp + (size_t)b * Tt * Tt;

    __shared__ _Float16 Ahl[2][2][8][512];    // 32 KB (A hi/lo dbuf)
    const _Float16* Th = Thi + (size_t)b * Tt * Dd;
    const _Float16* Tl = Tlo + (size_t)b * Tt * Dd;
    const _Float16* Xh = Xhi + (size_t)b * Tt * Dd;
    const _Float16* Xl = Xlo + (size_t)b * Tt * Dd;

    const int tid = threadIdx.x;
    const int w = tid >> 6, lane = tid & 63;
    const int lr = lane & 15, lq = lane >> 4;
    const int wr = (w >> 1) * 4, wc = (w & 1) * 4;

    f32x4 acc[4][4];
#pragma unroll
    for (int i = 0; i < 4; ++i)
#pragma unroll
        for (int j = 0; j < 4; ++j)
#pragma unroll
            for (int c = 0; c < 4; ++c) acc[i][j][c] = 0.f;

    auto stageA = [&](int bf, int kk) {
#pragma unroll
        for (int s2 = 0; s2 < 2; ++s2) {
            const int s = w * 2 + s2;
            const size_t ar = (size_t)(q0 + s * 16 + lr) * Dd + kk + lq * 8;
            GLD16(Th + ar, &Ahl[bf][0][s][0]);
            GLD16(Tl + ar, &Ahl[bf][1][s][0]);
        }
    };

    size_t bro[4];
#pragma unroll
    for (int j = 0; j < 4; ++j)
        bro[j] = (size_t)(j0 + (wc + j) * 16 + lr) * Dd + lq * 8;

    half8 Beh[4], Bel[4], Boh[4], Bol[4];
    auto loadB = [&](half8 (&bh)[4], half8 (&bl)[4], int kk) {
#pragma unroll
        for (int j = 0; j < 4; ++j) {
            bh[j] = *(const half8*)(Xh + bro[j] + kk);
            bl[j] = *(const half8*)(Xl + bro[j] + kk);
        }
    };
    auto domfma = [&](int bf, half8 (&bh)[4], half8 (&bl)[4]) {
        half8 ah[4], al[4];
#pragma unroll
        for (int i = 0; i < 4; ++i) {
            ah[i] = *(const half8*)&Ahl[bf][0][wr + i][lane * 8];
            al[i] = *(const half8*)&Ahl[bf][1][wr + i][lane * 8];
        }
#pragma unroll
        for (int i = 0; i < 4; ++i)
#pragma unroll
            for (int j = 0; j < 4; ++j) {
                acc[i][j] = __builtin_amdgcn_mfma_f32_16x16x32_f16(ah[i], bh[j], acc[i][j], 0, 0, 0);
                acc[i][j] = __builtin_amdgcn_mfma_f32_16x16x32_f16(ah[i], bl[j], acc[i][j], 0, 0, 0);
                acc[i][j] = __builtin_amdgcn_mfma_f32_16x16x32_f16(al[i], bh[j], acc[i][j], 0, 0, 0);
            }
    };

    // prologue: A(0)->buf0, B(0)->Be, B(1)->Bo
    stageA(0, 0);
    loadB(Beh, Bel, 0);
    loadB(Boh, Bol, 32);

    for (int i = 0; i < 32; i += 2) {
        // ---- even step i (A in buf0, B in Be)
        stageA(1, (i + 1) << 5);                 // A(i+1): i+1 <= 31 always
        WAIT_VM(12);                             // A(i)+B(i) landed
        BARRIER();
        SCHED_FENCE();
        domfma(0, Beh, Bel);
        if (i + 2 < 32) loadB(Beh, Bel, (i + 2) << 5);   // WAR after consume
        BARRIER();
        // ---- odd step i+1 (A in buf1, B in Bo)
        if (i + 2 < 32) {
            stageA(0, (i + 2) << 5);
            WAIT_VM(12);                         // A(i+1)+B(i+1) landed
        } else {
            WAIT_VM(0);
        }
        BARRIER();
        SCHED_FENCE();
        domfma(1, Boh, Bol);
        if (i + 3 < 32) loadB(Boh, Bol, (i + 3) << 5);
        BARRIER();
    }

    // masked + floored values in registers
    float sv[4][4][4];
#pragma unroll
    for (int i = 0; i < 4; ++i)
#pragma unroll
        for (int r = 0; r < 4; ++r) {
            const int q = q0 + (wr + i) * 16 + lq * 4 + r;
#pragma unroll
            for (int j = 0; j < 4; ++j) {
                const int jg = j0 + (wc + j) * 16 + lr;
                sv[i][j][r] = (jg <= q) ? floorf(acc[i][j][r] * 0.03125f) : -INFINITY;
            }
        }

    // per-column stats + P' write (reuse staging LDS: 16x128 partials + colmax)
    float* red  = (float*)&Ahl[0][0][0][0];   // [16][128]
    float* colm = red + 2048;                 // [128]
    __syncthreads();
    for (int e = tid; e < 2048; e += 256) red[e] = -INFINITY;
    __syncthreads();
    const int rowidx = (w * 4 + lq) * 128;
#pragma unroll
    for (int j = 0; j < 4; ++j) {
        const int c = (wc + j) * 16 + lr;
        float lm = -INFINITY;
#pragma unroll
        for (int i = 0; i < 4; ++i)
#pragma unroll
            for (int r = 0; r < 4; ++r) lm = fmaxf(lm, sv[i][j][r]);
        red[rowidx + c] = lm;
    }
    __syncthreads();
    if (tid < 128) {
        float m = -INFINITY;
#pragma unroll
        for (int e = 0; e < 16; ++e) m = fmaxf(m, red[e * 128 + tid]);
        colm[tid] = m;
    }
    __syncthreads();
    float ls[4];
#pragma unroll
    for (int j = 0; j < 4; ++j) {
        const int c = (wc + j) * 16 + lr;
        const int jg = j0 + c;
        const float m = colm[c];
        float s = 0.f;
#pragma unroll
        for (int i = 0; i < 4; ++i)
#pragma unroll
            for (int r = 0; r < 4; ++r) {
                const float e = __expf(sv[i][j][r] - m);   // masked -> exp(-inf)=0
                s += e;
                const int q = q0 + (wr + i) * 16 + lq * 4 + r;
                Pb[(size_t)q * Tt + jg] = f2h(e);
            }
        ls[j] = s;
    }
    __syncthreads();
    for (int e = tid; e < 2048; e += 256) red[e] = 0.f;
    __syncthreads();
#pragma unroll
    for (int j = 0; j < 4; ++j) red[rowidx + (wc + j) * 16 + lr] = ls[j];
    __syncthreads();
    if (tid < 128) {
        float l = 0.f;
#pragma unroll
        for (int e = 0; e < 16; ++e) l += red[e * 128 + tid];
        const size_t o = ((size_t)b * NCH + byi) * Tt + j0 + tid;
        Pm[o] = colm[tid];
        Pl[o] = l;
    }
}

// ---------------------------------------------------------------------------
// merge NCH=16 partials per column -> m, 1/l  (index-predicated: c >= j>>7)
// ---------------------------------------------------------------------------
__global__ __launch_bounds__(256) void colstats_merge_kernel(
    const float* __restrict__ Pm, const float* __restrict__ Pl,
    float* __restrict__ Mb, float* __restrict__ Lb)
{
    const int j = blockIdx.x * 256 + threadIdx.x;
    const int b = blockIdx.y;
    const int jt = j >> 7;
    float m = -INFINITY, l = 0.f;
    for (int c = jt; c < NCH; ++c) {
        const size_t pidx = ((size_t)b * NCH + c) * Tt + j;
        const float mi = Pm[pidx];
        if (mi == -INFINITY) continue;
        const float li = Pl[pidx];
        if (mi > m) { l = l * __expf(m - mi) + li; m = mi; }
        else        { l += li * __expf(mi - m); }
    }
    Mb[(size_t)b * Tt + j] = m;
    Lb[(size_t)b * Tt + j] = (l > 0.f) ? 1.f / l : 0.f;
}

// ---------------------------------------------------------------------------
// context = P @ V.  A = P'(f16) * c_k, c_k precomputed in LDS.
// Pipelined (As dbuf + depth-2 P reg prefetch + counted vmcnt, 1 barrier/step).
// WORK-BALANCED mapping (round-8, measured win).
// ---------------------------------------------------------------------------
__global__ __launch_bounds__(256) void context_mfma_kernel(
    const _Float16* __restrict__ Pp, const float* __restrict__ Pm,
    const float* __restrict__ Mb, const float* __restrict__ Lb,
    const _Float16* __restrict__ Vt, float* __restrict__ Out)
{
    __shared__ _Float16 As[2][8][512];   // P tile f16 dbuf
    __shared__ _Float16 Bl[2][8][512];   // V dbuf
    __shared__ float cbuf[2048];         // per-k correction

    const int f   = blockIdx.x;              // 0..511
    const int xcd = f & 7;
    const int c   = (f >> 3) & 31;           // CU within XCD (assumed)
    const int p   = f >> 8;                  // resident slot (assumed, 0..1)
    const int b   = xcd >> 1;                // batch 0..3
    const int bx  = c & 7;
    const int base = ((xcd & 1) << 3) + ((c >> 3) << 1);   // 0,2,..,14
    const int by  = p ? (15 - base) : base;
    const int d0 = bx * 128;
    const int q0 = by * 128;
    const _Float16* Pb = Pp + (size_t)b * Tt * Tt;
    const float* Pmb = Pm + ((size_t)b * NCH + by) * Tt;
    const float* Mp = Mb + (size_t)b * Tt;
    const float* Lp = Lb + (size_t)b * Tt;
    const _Float16* Vb = Vt + (size_t)b * Dd * Tt;
    float* Ob = Out + (size_t)b * Tt * Dd;

    const int tid = threadIdx.x;
    const int w = tid >> 6, lane = tid & 63;
    const int lr = lane & 15, lq = lane >> 4;
    const int wr = (w >> 1) * 4, wc = (w & 1) * 4;
    const int kmax = q0 + 128;
    const int nstep = kmax >> 5;             // 4*(by+1): even, >= 4

    // precompute c[k] (one pass, cooperative)
    for (int k = tid; k < kmax; k += 256)
        cbuf[k] = __expf(Pmb[k] - Mp[k]) * Lp[k];

    f32x4 acc[4][4];
#pragma unroll
    for (int i = 0; i < 4; ++i)
#pragma unroll
        for (int j = 0; j < 4; ++j)
#pragma unroll
            for (int c2 = 0; c2 < 4; ++c2) acc[i][j][c2] = 0.f;

    half8 RpA[2], RpB[2];
    auto loadP = [&](half8 (&R)[2], int k0) {
#pragma unroll
        for (int s2 = 0; s2 < 2; ++s2) {
            const int s = w * 2 + s2;
            R[s2] = *(const half8*)(Pb + (size_t)(q0 + s * 16 + lr) * Tt + k0 + lq * 8);
        }
    };
    auto issueV = [&](int bf, int k0) {
#pragma unroll
        for (int s2 = 0; s2 < 2; ++s2) {
            const int s = w * 2 + s2;
            GLD16(Vb + (size_t)(d0 + s * 16 + lr) * Tt + k0 + lq * 8, &Bl[bf][s][0]);
        }
    };
    auto writeA = [&](int bf, half8 (&R)[2], int k0) {
        const float* cp = cbuf + k0 + lq * 8;
        float cv[8];
#pragma unroll
        for (int e = 0; e < 8; ++e) cv[e] = cp[e];
#pragma unroll
        for (int s2 = 0; s2 < 2; ++s2) {
            const int s = w * 2 + s2;
            half8 out;
#pragma unroll
            for (int e = 0; e < 8; ++e) out[e] = f2h((float)R[s2][e] * cv[e]);
            *(half8*)&As[bf][s][lane * 8] = out;
        }
    };
    auto domfma = [&](int bf) {
        half8 a[4], b2[4];
#pragma unroll
        for (int i = 0; i < 4; ++i) a[i] = *(const half8*)&As[bf][wr + i][lane * 8];
#pragma unroll
        for (int j = 0; j < 4; ++j) b2[j] = *(const half8*)&Bl[bf][wc + j][lane * 8];
#pragma unroll
        for (int i = 0; i < 4; ++i)
#pragma unroll
            for (int j = 0; j < 4; ++j)
                acc[i][j] = __builtin_amdgcn_mfma_f32_16x16x32_f16(a[i], b2[j], acc[i][j], 0, 0, 0);
    };

    __syncthreads();          // cbuf ready

    // prologue: V(0)->Bl0, P(0)->RpA, P(1)->RpB; build As0
    issueV(0, 0);
    loadP(RpA, 0);
    loadP(RpB, 32);
    WAIT_VM(2);               // V(0)+RpA landed (RpB still flying)
    writeA(0, RpA, 0);
    WAIT_LGKM0();
    BARRIER();

    for (int i = 0; i < nstep; i += 2) {
        // ---- even step i: compute buf0; build buf1 from RpB; prefetch P(i+2)->RpA
        {
            const bool pfP = (i + 2 < nstep);
            issueV(1, (i + 1) << 5);
            if (pfP) loadP(RpA, (i + 2) << 5);
            domfma(0);
            if (pfP) WAIT_VM(4); else WAIT_VM(2);   // RpB landed
            writeA(1, RpB, (i + 1) << 5);
            if (pfP) WAIT_VM(2); else WAIT_VM(0);   // V(i+1) landed (RpA may fly)
            WAIT_LGKM0();                            // my As writes visible
            BARRIER();
        }
        // ---- odd step i+1: compute buf1; build buf0 from RpA; prefetch P(i+3)->RpB
        {
            const bool pfV = (i + 2 < nstep);
            const bool pfP = (i + 3 < nstep);
            if (pfV) issueV(0, (i + 2) << 5);
            if (pfP) loadP(RpB, (i + 3) << 5);
            domfma(1);
            if (pfV) {
                if (pfP) WAIT_VM(4); else WAIT_VM(2);   // RpA landed
                writeA(0, RpA, (i + 2) << 5);
                if (pfP) WAIT_VM(2); else WAIT_VM(0);   // V(i+2) landed
                WAIT_LGKM0();
            }
            BARRIER();
        }
    }

#pragma unroll
    for (int i = 0; i < 4; ++i)
#pragma unroll
        for (int r2 = 0; r2 < 4; ++r2) {
            const int row = q0 + (wr + i) * 16 + lq * 4 + r2;
#pragma unroll
            for (int j = 0; j < 4; ++j)
                Ob[(size_t)row * Dd + d0 + (wc + j) * 16 + lr] = acc[i][j][r2];
        }
}

}  // namespace

extern "C" void kernel_launch(void* const* d_in, const int* in_sizes, int n_in,
                              void* d_out, int out_size, void* d_ws, size_t ws_size,
                              hipStream_t stream)
{
    const float* X  = (const float*)d_in[0];
    const float* Wq = (const float*)d_in[1];
    const float* Wk = (const float*)d_in[2];
    const float* Wv = (const float*)d_in[3];

    char* ws = (char*)d_ws;
    const size_t MB = 1024 * 1024;
    _Float16* Xhi  = (_Float16*)ws;
    _Float16* Xlo  = (_Float16*)(ws + 16 * MB);
    _Float16* Wqh  = (_Float16*)(ws + 32 * MB);
    _Float16* Wql  = (_Float16*)(ws + 34 * MB);
    _Float16* Wkh  = (_Float16*)(ws + 36 * MB);
    _Float16* Wkl  = (_Float16*)(ws + 38 * MB);
    _Float16* WvTh = (_Float16*)(ws + 40 * MB);
    _Float16* GTh  = (_Float16*)(ws + 44 * MB);
    _Float16* GTl  = (_Float16*)(ws + 46 * MB);
    _Float16* Thi  = (_Float16*)(ws + 48 * MB);
    _Float16* Tlo  = (_Float16*)(ws + 64 * MB);
    _Float16* Vt   = (_Float16*)(ws + 80 * MB);
    _Float16* Pp   = (_Float16*)(ws + 112 * MB);      // 32 MB f16 P'
    float*    Mb   = (float*)(ws + 176 * MB);
    float*    Lb   = Mb + (size_t)Bb * Tt;
    float*    Pm   = Lb + (size_t)Bb * Tt;
    float*    Pl   = Pm + (size_t)Bb * NCH * Tt;
    float*    Out  = (float*)d_out;

    convert_all_kernel<<<10496, 256, 0, stream>>>(X, Wq, Wk, Wv, Xhi, Xlo,
                                                  Wqh, Wql, Wkh, Wkl, WvTh);
    gt_kernel<<<dim3(16, 16), 256, 0, stream>>>(Wkh, Wkl, Wqh, Wql, GTh, GTl);
    tv_kernel<<<dim3(1024), 256, 0, stream>>>(Xhi, Xlo, GTh, GTl, WvTh, Thi, Tlo, Vt);
    scores_mfma_kernel<<<dim3(544), 256, 0, stream>>>(Thi, Tlo, Xhi, Xlo, Pp, Pm, Pl);
    colstats_merge_kernel<<<dim3(Tt / 256, Bb), 256, 0, stream>>>(Pm, Pl, Mb, Lb);
    context_mfma_kernel<<<dim3(512), 256, 0, stream>>>(Pp, Pm, Mb, Lb, Vt, Out);
}

// Round 11
// 396.495 us; speedup vs baseline: 1.2904x; 1.2904x over previous
//
#include <hip/hip_runtime.h>
#include <math.h>

typedef _Float16 half4 __attribute__((ext_vector_type(4)));
typedef _Float16 half8 __attribute__((ext_vector_type(8)));
typedef float f32x4 __attribute__((ext_vector_type(4)));

#define GLD16(gptr, lptr)                                                     \
    __builtin_amdgcn_global_load_lds(                                         \
        (const __attribute__((address_space(1))) unsigned int*)(gptr),        \
        (__attribute__((address_space(3))) unsigned int*)(lptr), 16, 0, 0)

#define WAIT_VM(N) asm volatile("s_waitcnt vmcnt(" #N ")" ::: "memory")
#define WAIT_LGKM0() asm volatile("s_waitcnt lgkmcnt(0)" ::: "memory")
#define BARRIER()  __builtin_amdgcn_s_barrier()
#define SCHED_FENCE() __builtin_amdgcn_sched_barrier(0)

namespace {

constexpr int Bb = 4;
constexpr int Tt = 2048;
constexpr int Dd = 1024;
constexpr int BT = Bb * Tt;   // 8192
constexpr int NCH = 16;       // stats chunks = 128-row tiles

__device__ inline _Float16 f2h(float f) { return (_Float16)f; }

// ---------------------------------------------------------------------------
// FUSED converts: X -> Xhi/Xlo ; Wq,Wk -> hi/lo ; Wv -> WvT hi.
// ---------------------------------------------------------------------------
__global__ __launch_bounds__(256) void convert_all_kernel(
    const float* __restrict__ X,  const float* __restrict__ Wq,
    const float* __restrict__ Wk, const float* __restrict__ Wv,
    _Float16* __restrict__ Xhi, _Float16* __restrict__ Xlo,
    _Float16* __restrict__ Wqh, _Float16* __restrict__ Wql,
    _Float16* __restrict__ Wkh, _Float16* __restrict__ Wkl,
    _Float16* __restrict__ WvTh)
{
    __shared__ float tile[64][65];
    const int f = blockIdx.x;
    if (f < 8192) {
        const int idx = f * 1024 + threadIdx.x * 4;
        const float4 v = *(const float4*)(X + idx);
        const float a[4] = {v.x, v.y, v.z, v.w};
        half4 h, l;
#pragma unroll
        for (int i = 0; i < 4; ++i) {
            h[i] = f2h(a[i]);
            l[i] = f2h(a[i] - (float)h[i]);
        }
        *(half4*)(Xhi + idx) = h;
        *(half4*)(Xlo + idx) = l;
    } else if (f < 10240) {
        const int g = f - 8192;
        const int mat = g >> 10;
        const float* W = mat ? Wk : Wq;
        _Float16* Hh = mat ? Wkh : Wqh;
        _Float16* Ll = mat ? Wkl : Wql;
        const int idx = (g & 1023) * 1024 + threadIdx.x * 4;
        const float4 v = *(const float4*)(W + idx);
        const float a[4] = {v.x, v.y, v.z, v.w};
        half4 h, l;
#pragma unroll
        for (int i = 0; i < 4; ++i) {
            h[i] = f2h(a[i]);
            l[i] = f2h(a[i] - (float)h[i]);
        }
        *(half4*)(Hh + idx) = h;
        *(half4*)(Ll + idx) = l;
    } else {
        const int g = f - 10240;
        const int n0 = (g & 15) * 64, k0 = (g >> 4) * 64;
        const int tx = threadIdx.x & 63, ty = threadIdx.x >> 6;
#pragma unroll
        for (int i = 0; i < 16; ++i)
            tile[ty + i * 4][tx] = Wv[(size_t)(k0 + ty + i * 4) * Dd + n0 + tx];
        __syncthreads();
#pragma unroll
        for (int i = 0; i < 16; ++i) {
            const float v = tile[tx][ty + i * 4];
            WvTh[(size_t)(n0 + ty + i * 4) * Dd + k0 + tx] = f2h(v);
        }
    }
}

// ---------------------------------------------------------------------------
// GT[s][r] = sum_a Wk[s][a] * Wq[r][a]   (counted-vmcnt pipeline)
// ---------------------------------------------------------------------------
__global__ __launch_bounds__(256) void gt_kernel(
    const _Float16* __restrict__ Wkh, const _Float16* __restrict__ Wkl,
    const _Float16* __restrict__ Wqh, const _Float16* __restrict__ Wql,
    _Float16* __restrict__ GTh, _Float16* __restrict__ GTl)
{
    __shared__ _Float16 Ahl[2][2][4][512];
    __shared__ _Float16 Bhl[2][2][4][512];

    const int n0 = blockIdx.x * 64;
    const int m0 = blockIdx.y * 64;
    const int tid = threadIdx.x;
    const int w = tid >> 6, lane = tid & 63;
    const int lr = lane & 15, lq = lane >> 4;
    const int wi = (w >> 1) * 2, wj = (w & 1) * 2;

    f32x4 acc[2][2];
#pragma unroll
    for (int i = 0; i < 2; ++i)
#pragma unroll
        for (int j = 0; j < 2; ++j)
#pragma unroll
            for (int c = 0; c < 4; ++c) acc[i][j][c] = 0.f;

    auto stage = [&](int bf, int kk) {
        const int s = w;
        const size_t ar = (size_t)(m0 + s * 16 + lr) * Dd + kk + lq * 8;
        const size_t br = (size_t)(n0 + s * 16 + lr) * Dd + kk + lq * 8;
        GLD16(Wkh + ar, &Ahl[bf][0][s][0]);
        GLD16(Wkl + ar, &Ahl[bf][1][s][0]);
        GLD16(Wqh + br, &Bhl[bf][0][s][0]);
        GLD16(Wql + br, &Bhl[bf][1][s][0]);
    };

    stage(0, 0);
    int ib = 0;
    for (int step = 0; step < 32; ++step, ib ^= 1) {
        if (step < 31) {
            stage(ib ^ 1, (step + 1) << 5);
            WAIT_VM(4);
        } else {
            WAIT_VM(0);
        }
        BARRIER();
        SCHED_FENCE();
        half8 ah[2], al[2], bh[2], bl[2];
#pragma unroll
        for (int i = 0; i < 2; ++i) {
            ah[i] = *(const half8*)&Ahl[ib][0][wi + i][lane * 8];
            al[i] = *(const half8*)&Ahl[ib][1][wi + i][lane * 8];
        }
#pragma unroll
        for (int j = 0; j < 2; ++j) {
            bh[j] = *(const half8*)&Bhl[ib][0][wj + j][lane * 8];
            bl[j] = *(const half8*)&Bhl[ib][1][wj + j][lane * 8];
        }
#pragma unroll
        for (int i = 0; i < 2; ++i)
#pragma unroll
            for (int j = 0; j < 2; ++j) {
                acc[i][j] = __builtin_amdgcn_mfma_f32_16x16x32_f16(ah[i], bh[j], acc[i][j], 0, 0, 0);
                acc[i][j] = __builtin_amdgcn_mfma_f32_16x16x32_f16(ah[i], bl[j], acc[i][j], 0, 0, 0);
                acc[i][j] = __builtin_amdgcn_mfma_f32_16x16x32_f16(al[i], bh[j], acc[i][j], 0, 0, 0);
            }
        BARRIER();
    }

#pragma unroll
    for (int i = 0; i < 2; ++i)
#pragma unroll
        for (int r = 0; r < 4; ++r) {
            const int row = m0 + (wi + i) * 16 + lq * 4 + r;
#pragma unroll
            for (int j = 0; j < 2; ++j) {
                const int col = n0 + (wj + j) * 16 + lr;
                const float v = acc[i][j][r];
                const _Float16 h = f2h(v);
                GTh[(size_t)row * Dd + col] = h;
                GTl[(size_t)row * Dd + col] = f2h(v - (float)h);
            }
        }
}

// ---------------------------------------------------------------------------
// FUSED  T = X*G (3-product hi/lo)  +  V = X*Wv (single product).
// ROLE-BALANCED mapping (round-8, measured win). v-role epilogue writes Vt.
// ---------------------------------------------------------------------------
__global__ __launch_bounds__(256, 2) void tv_kernel(
    const _Float16* __restrict__ Xhi, const _Float16* __restrict__ Xlo,
    const _Float16* __restrict__ GTh, const _Float16* __restrict__ GTl,
    const _Float16* __restrict__ WvTh,
    _Float16* __restrict__ Thi, _Float16* __restrict__ Tlo,
    _Float16* __restrict__ Vt)
{
    __shared__ _Float16 smem[32768];   // 64 KB: staging dbuf; v-role epilogue scratch
    auto A_ = [&](int bf, int hl, int s) -> _Float16* {
        return smem + ((bf * 2 + hl) * 8 + s) * 512;
    };
    auto B_ = [&](int bf, int hl, int s) -> _Float16* {
        return smem + 16384 + ((bf * 2 + hl) * 8 + s) * 512;
    };

    const int f   = blockIdx.x;           // 0..1023
    const int xcd = f & 7;
    const int c   = (f >> 3) & 31;        // CU within XCD (assumed)
    const int p   = f >> 8;               // resident slot (assumed)
    const int mb  = xcd * 8 + (c & 7);    // m-panel 0..63
    const int sub = p * 4 + (c >> 3);     // 0..15; p<2 -> t-role
    const int m0 = mb * 128;
    const int n0 = (sub & 7) * 128;

    const int tid = threadIdx.x;
    const int w = tid >> 6, lane = tid & 63;
    const int lr = lane & 15, lq = lane >> 4;
    const int wr = (w >> 1) * 4, wc = (w & 1) * 4;

    f32x4 acc[4][4];
#pragma unroll
    for (int i = 0; i < 4; ++i)
#pragma unroll
        for (int j = 0; j < 4; ++j)
#pragma unroll
            for (int c2 = 0; c2 < 4; ++c2) acc[i][j][c2] = 0.f;

    if (sub < 8) {
        // ----- t-role: 3-product hi/lo -----
        auto stage = [&](int bf, int kk) {
#pragma unroll
            for (int s2 = 0; s2 < 2; ++s2) {
                const int s = w * 2 + s2;
                const size_t ar = (size_t)(m0 + s * 16 + lr) * Dd + kk + lq * 8;
                const size_t br = (size_t)(n0 + s * 16 + lr) * Dd + kk + lq * 8;
                GLD16(Xhi + ar, A_(bf, 0, s));
                GLD16(Xlo + ar, A_(bf, 1, s));
                GLD16(GTh + br, B_(bf, 0, s));
                GLD16(GTl + br, B_(bf, 1, s));
            }
        };
        stage(0, 0);
        int ib = 0;
        for (int step = 0; step < 32; ++step, ib ^= 1) {
            if (step < 31) {
                stage(ib ^ 1, (step + 1) << 5);
                WAIT_VM(8);
            } else {
                WAIT_VM(0);
            }
            BARRIER();
            SCHED_FENCE();
            half8 ah[4], al[4], bh[4], bl[4];
#pragma unroll
            for (int i = 0; i < 4; ++i) {
                ah[i] = *(const half8*)(A_(ib, 0, wr + i) + lane * 8);
                al[i] = *(const half8*)(A_(ib, 1, wr + i) + lane * 8);
            }
#pragma unroll
            for (int j = 0; j < 4; ++j) {
                bh[j] = *(const half8*)(B_(ib, 0, wc + j) + lane * 8);
                bl[j] = *(const half8*)(B_(ib, 1, wc + j) + lane * 8);
            }
#pragma unroll
            for (int i = 0; i < 4; ++i)
#pragma unroll
                for (int j = 0; j < 4; ++j) {
                    acc[i][j] = __builtin_amdgcn_mfma_f32_16x16x32_f16(ah[i], bh[j], acc[i][j], 0, 0, 0);
                    acc[i][j] = __builtin_amdgcn_mfma_f32_16x16x32_f16(ah[i], bl[j], acc[i][j], 0, 0, 0);
                    acc[i][j] = __builtin_amdgcn_mfma_f32_16x16x32_f16(al[i], bh[j], acc[i][j], 0, 0, 0);
                }
            BARRIER();
        }
#pragma unroll
        for (int i = 0; i < 4; ++i)
#pragma unroll
            for (int r = 0; r < 4; ++r) {
                const int row = m0 + (wr + i) * 16 + lq * 4 + r;
#pragma unroll
                for (int j = 0; j < 4; ++j) {
                    const int col = n0 + (wc + j) * 16 + lr;
                    const float v = acc[i][j][r];
                    const _Float16 h = f2h(v);
                    Thi[(size_t)row * Dd + col] = h;
                    Tlo[(size_t)row * Dd + col] = f2h(v - (float)h);
                }
            }
    } else {
        // ----- v-role: single product -----
        auto stage = [&](int bf, int kk) {
#pragma unroll
            for (int s2 = 0; s2 < 2; ++s2) {
                const int s = w * 2 + s2;
                GLD16(Xhi + (size_t)(m0 + s * 16 + lr) * Dd + kk + lq * 8, A_(bf, 0, s));
                GLD16(WvTh + (size_t)(n0 + s * 16 + lr) * Dd + kk + lq * 8, B_(bf, 0, s));
            }
        };
        stage(0, 0);
        int ib = 0;
        for (int step = 0; step < 32; ++step, ib ^= 1) {
            if (step < 31) {
                stage(ib ^ 1, (step + 1) << 5);
                WAIT_VM(4);
            } else {
                WAIT_VM(0);
            }
            BARRIER();
            SCHED_FENCE();
            half8 a[4], b2[4];
#pragma unroll
            for (int i = 0; i < 4; ++i) a[i] = *(const half8*)(A_(ib, 0, wr + i) + lane * 8);
#pragma unroll
            for (int j = 0; j < 4; ++j) b2[j] = *(const half8*)(B_(ib, 0, wc + j) + lane * 8);
#pragma unroll
            for (int i = 0; i < 4; ++i)
#pragma unroll
                for (int j = 0; j < 4; ++j)
                    acc[i][j] = __builtin_amdgcn_mfma_f32_16x16x32_f16(a[i], b2[j], acc[i][j], 0, 0, 0);
            BARRIER();
        }
        // ----- epilogue: write Vt[b][d][t] (pure transpose) via LDS -----
        __syncthreads();
#pragma unroll
        for (int i = 0; i < 4; ++i)
#pragma unroll
            for (int r2 = 0; r2 < 4; ++r2) {
                const int rloc = (wr + i) * 16 + lq * 4 + r2;   // local t-row
#pragma unroll
                for (int j = 0; j < 4; ++j) {
                    const int cloc = (wc + j) * 16 + lr;        // local d-col
                    smem[cloc * 136 + rloc] = f2h(acc[i][j][r2]);
                }
            }
        __syncthreads();
        const int b2i = m0 >> 11;            // batch (panels never straddle)
        const int t0  = m0 & 2047;
        const int dloc = tid >> 1, tl = (tid & 1) * 64;
        _Float16* vp = Vt + (size_t)b2i * Dd * Tt + (size_t)(n0 + dloc) * Tt + t0 + tl;
#pragma unroll
        for (int e = 0; e < 8; ++e)
            *(half8*)(vp + e * 8) = *(const half8*)&smem[dloc * 136 + tl + e * 8];
    }
}

// ---------------------------------------------------------------------------
// scores + FUSED column stats + P' write.  P' = f16(exp(Sf - chunkmax)).
// Round-8 structure (best measured): A+B hi/lo via GLD16 dbuf, counted vmcnt.
// ---------------------------------------------------------------------------
__global__ __launch_bounds__(256, 2) void scores_mfma_kernel(
    const _Float16* __restrict__ Thi, const _Float16* __restrict__ Tlo,
    const _Float16* __restrict__ Xhi, const _Float16* __restrict__ Xlo,
    _Float16* __restrict__ Pp, float* __restrict__ Pm, float* __restrict__ Pl)
{
    const int f  = blockIdx.x;                // 0..543
    const int fp = (f & 7) * 68 + (f >> 3);   // chunked bijective
    const int b = fp / 136;
    const int t = fp - b * 136;
    int byi = (int)((sqrtf(8.f * t + 1.f) - 1.f) * 0.5f);
    if ((byi + 1) * (byi + 2) / 2 <= t) ++byi;
    if (byi * (byi + 1) / 2 > t) --byi;
    const int bxi = t - byi * (byi + 1) / 2;
    const int j0 = bxi * 128, q0 = byi * 128;
    _Float16* Pb = Pp + (size_t)b * Tt * Tt;

    __shared__ _Float16 Ahl[2][2][8][512];
    __shared__ _Float16 Bhl[2][2][8][512];
    const _Float16* Th = Thi + (size_t)b * Tt * Dd;
    const _Float16* Tl = Tlo + (size_t)b * Tt * Dd;
    const _Float16* Xh = Xhi + (size_t)b * Tt * Dd;
    const _Float16* Xl = Xlo + (size_t)b * Tt * Dd;

    const int tid = threadIdx.x;
    const int w = tid >> 6, lane = tid & 63;
    const int lr = lane & 15, lq = lane >> 4;
    const int wr = (w >> 1) * 4, wc = (w & 1) * 4;

    f32x4 acc[4][4];
#pragma unroll
    for (int i = 0; i < 4; ++i)
#pragma unroll
        for (int j = 0; j < 4; ++j)
#pragma unroll
            for (int c = 0; c < 4; ++c) acc[i][j][c] = 0.f;

    auto stage = [&](int bf, int kk) {
#pragma unroll
        for (int s2 = 0; s2 < 2; ++s2) {
            const int s = w * 2 + s2;
            const size_t ar = (size_t)(q0 + s * 16 + lr) * Dd + kk + lq * 8;
            const size_t br = (size_t)(j0 + s * 16 + lr) * Dd + kk + lq * 8;
            GLD16(Th + ar, &Ahl[bf][0][s][0]);
            GLD16(Tl + ar, &Ahl[bf][1][s][0]);
            GLD16(Xh + br, &Bhl[bf][0][s][0]);
            GLD16(Xl + br, &Bhl[bf][1][s][0]);
        }
    };

    stage(0, 0);
    int ib = 0;
    for (int step = 0; step < 32; ++step, ib ^= 1) {
        if (step < 31) {
            stage(ib ^ 1, (step + 1) << 5);
            WAIT_VM(8);
        } else {
            WAIT_VM(0);
        }
        BARRIER();
        SCHED_FENCE();
        half8 ah[4], al[4], bh[4], bl[4];
#pragma unroll
        for (int i = 0; i < 4; ++i) {
            ah[i] = *(const half8*)&Ahl[ib][0][wr + i][lane * 8];
            al[i] = *(const half8*)&Ahl[ib][1][wr + i][lane * 8];
        }
#pragma unroll
        for (int j = 0; j < 4; ++j) {
            bh[j] = *(const half8*)&Bhl[ib][0][wc + j][lane * 8];
            bl[j] = *(const half8*)&Bhl[ib][1][wc + j][lane * 8];
        }
#pragma unroll
        for (int i = 0; i < 4; ++i)
#pragma unroll
            for (int j = 0; j < 4; ++j) {
                acc[i][j] = __builtin_amdgcn_mfma_f32_16x16x32_f16(ah[i], bh[j], acc[i][j], 0, 0, 0);
                acc[i][j] = __builtin_amdgcn_mfma_f32_16x16x32_f16(ah[i], bl[j], acc[i][j], 0, 0, 0);
                acc[i][j] = __builtin_amdgcn_mfma_f32_16x16x32_f16(al[i], bh[j], acc[i][j], 0, 0, 0);
            }
        BARRIER();
    }

    // masked + floored values in registers
    float sv[4][4][4];
#pragma unroll
    for (int i = 0; i < 4; ++i)
#pragma unroll
        for (int r = 0; r < 4; ++r) {
            const int q = q0 + (wr + i) * 16 + lq * 4 + r;
#pragma unroll
            for (int j = 0; j < 4; ++j) {
                const int jg = j0 + (wc + j) * 16 + lr;
                sv[i][j][r] = (jg <= q) ? floorf(acc[i][j][r] * 0.03125f) : -INFINITY;
            }
        }

    // per-column stats + P' write (reuse staging LDS: 16x128 partials + colmax)
    float* red  = (float*)&Ahl[0][0][0][0];   // [16][128]
    float* colm = red + 2048;                 // [128]
    __syncthreads();
    for (int e = tid; e < 2048; e += 256) red[e] = -INFINITY;
    __syncthreads();
    const int rowidx = (w * 4 + lq) * 128;
#pragma unroll
    for (int j = 0; j < 4; ++j) {
        const int c = (wc + j) * 16 + lr;
        float lm = -INFINITY;
#pragma unroll
        for (int i = 0; i < 4; ++i)
#pragma unroll
            for (int r = 0; r < 4; ++r) lm = fmaxf(lm, sv[i][j][r]);
        red[rowidx + c] = lm;
    }
    __syncthreads();
    if (tid < 128) {
        float m = -INFINITY;
#pragma unroll
        for (int e = 0; e < 16; ++e) m = fmaxf(m, red[e * 128 + tid]);
        colm[tid] = m;
    }
    __syncthreads();
    float ls[4];
#pragma unroll
    for (int j = 0; j < 4; ++j) {
        const int c = (wc + j) * 16 + lr;
        const int jg = j0 + c;
        const float m = colm[c];
        float s = 0.f;
#pragma unroll
        for (int i = 0; i < 4; ++i)
#pragma unroll
            for (int r = 0; r < 4; ++r) {
                const float e = __expf(sv[i][j][r] - m);   // masked -> exp(-inf)=0
                s += e;
                const int q = q0 + (wr + i) * 16 + lq * 4 + r;
                Pb[(size_t)q * Tt + jg] = f2h(e);
            }
        ls[j] = s;
    }
    __syncthreads();
    for (int e = tid; e < 2048; e += 256) red[e] = 0.f;
    __syncthreads();
#pragma unroll
    for (int j = 0; j < 4; ++j) red[rowidx + (wc + j) * 16 + lr] = ls[j];
    __syncthreads();
    if (tid < 128) {
        float l = 0.f;
#pragma unroll
        for (int e = 0; e < 16; ++e) l += red[e * 128 + tid];
        const size_t o = ((size_t)b * NCH + byi) * Tt + j0 + tid;
        Pm[o] = colm[tid];
        Pl[o] = l;
    }
}

// ---------------------------------------------------------------------------
// merge NCH=16 partials per column -> m, 1/l  (index-predicated: c >= j>>7)
// ---------------------------------------------------------------------------
__global__ __launch_bounds__(256) void colstats_merge_kernel(
    const float* __restrict__ Pm, const float* __restrict__ Pl,
    float* __restrict__ Mb, float* __restrict__ Lb)
{
    const int j = blockIdx.x * 256 + threadIdx.x;
    const int b = blockIdx.y;
    const int jt = j >> 7;
    float m = -INFINITY, l = 0.f;
    for (int c = jt; c < NCH; ++c) {
        const size_t pidx = ((size_t)b * NCH + c) * Tt + j;
        const float mi = Pm[pidx];
        if (mi == -INFINITY) continue;
        const float li = Pl[pidx];
        if (mi > m) { l = l * __expf(m - mi) + li; m = mi; }
        else        { l += li * __expf(mi - m); }
    }
    Mb[(size_t)b * Tt + j] = m;
    Lb[(size_t)b * Tt + j] = (l > 0.f) ? 1.f / l : 0.f;
}

// ---------------------------------------------------------------------------
// context = P @ V.  A = P'(f16) * c_k, c_k precomputed in LDS.
// Pipelined (As dbuf + depth-2 P reg prefetch + counted vmcnt, 1 barrier/step).
// WORK-BALANCED mapping (round-8, measured win).
// ---------------------------------------------------------------------------
__global__ __launch_bounds__(256) void context_mfma_kernel(
    const _Float16* __restrict__ Pp, const float* __restrict__ Pm,
    const float* __restrict__ Mb, const float* __restrict__ Lb,
    const _Float16* __restrict__ Vt, float* __restrict__ Out)
{
    __shared__ _Float16 As[2][8][512];   // P tile f16 dbuf
    __shared__ _Float16 Bl[2][8][512];   // V dbuf
    __shared__ float cbuf[2048];         // per-k correction

    const int f   = blockIdx.x;              // 0..511
    const int xcd = f & 7;
    const int c   = (f >> 3) & 31;           // CU within XCD (assumed)
    const int p   = f >> 8;                  // resident slot (assumed, 0..1)
    const int b   = xcd >> 1;                // batch 0..3
    const int bx  = c & 7;
    const int base = ((xcd & 1) << 3) + ((c >> 3) << 1);   // 0,2,..,14
    const int by  = p ? (15 - base) : base;
    const int d0 = bx * 128;
    const int q0 = by * 128;
    const _Float16* Pb = Pp + (size_t)b * Tt * Tt;
    const float* Pmb = Pm + ((size_t)b * NCH + by) * Tt;
    const float* Mp = Mb + (size_t)b * Tt;
    const float* Lp = Lb + (size_t)b * Tt;
    const _Float16* Vb = Vt + (size_t)b * Dd * Tt;
    float* Ob = Out + (size_t)b * Tt * Dd;

    const int tid = threadIdx.x;
    const int w = tid >> 6, lane = tid & 63;
    const int lr = lane & 15, lq = lane >> 4;
    const int wr = (w >> 1) * 4, wc = (w & 1) * 4;
    const int kmax = q0 + 128;
    const int nstep = kmax >> 5;             // 4*(by+1): even, >= 4

    // precompute c[k] (one pass, cooperative)
    for (int k = tid; k < kmax; k += 256)
        cbuf[k] = __expf(Pmb[k] - Mp[k]) * Lp[k];

    f32x4 acc[4][4];
#pragma unroll
    for (int i = 0; i < 4; ++i)
#pragma unroll
        for (int j = 0; j < 4; ++j)
#pragma unroll
            for (int c2 = 0; c2 < 4; ++c2) acc[i][j][c2] = 0.f;

    half8 RpA[2], RpB[2];
    auto loadP = [&](half8 (&R)[2], int k0) {
#pragma unroll
        for (int s2 = 0; s2 < 2; ++s2) {
            const int s = w * 2 + s2;
            R[s2] = *(const half8*)(Pb + (size_t)(q0 + s * 16 + lr) * Tt + k0 + lq * 8);
        }
    };
    auto issueV = [&](int bf, int k0) {
#pragma unroll
        for (int s2 = 0; s2 < 2; ++s2) {
            const int s = w * 2 + s2;
            GLD16(Vb + (size_t)(d0 + s * 16 + lr) * Tt + k0 + lq * 8, &Bl[bf][s][0]);
        }
    };
    auto writeA = [&](int bf, half8 (&R)[2], int k0) {
        const float* cp = cbuf + k0 + lq * 8;
        float cv[8];
#pragma unroll
        for (int e = 0; e < 8; ++e) cv[e] = cp[e];
#pragma unroll
        for (int s2 = 0; s2 < 2; ++s2) {
            const int s = w * 2 + s2;
            half8 out;
#pragma unroll
            for (int e = 0; e < 8; ++e) out[e] = f2h((float)R[s2][e] * cv[e]);
            *(half8*)&As[bf][s][lane * 8] = out;
        }
    };
    auto domfma = [&](int bf) {
        half8 a[4], b2[4];
#pragma unroll
        for (int i = 0; i < 4; ++i) a[i] = *(const half8*)&As[bf][wr + i][lane * 8];
#pragma unroll
        for (int j = 0; j < 4; ++j) b2[j] = *(const half8*)&Bl[bf][wc + j][lane * 8];
#pragma unroll
        for (int i = 0; i < 4; ++i)
#pragma unroll
            for (int j = 0; j < 4; ++j)
                acc[i][j] = __builtin_amdgcn_mfma_f32_16x16x32_f16(a[i], b2[j], acc[i][j], 0, 0, 0);
    };

    __syncthreads();          // cbuf ready

    // prologue: V(0)->Bl0, P(0)->RpA, P(1)->RpB; build As0
    issueV(0, 0);
    loadP(RpA, 0);
    loadP(RpB, 32);
    WAIT_VM(2);               // V(0)+RpA landed (RpB still flying)
    writeA(0, RpA, 0);
    WAIT_LGKM0();
    BARRIER();

    for (int i = 0; i < nstep; i += 2) {
        // ---- even step i: compute buf0; build buf1 from RpB; prefetch P(i+2)->RpA
        {
            const bool pfP = (i + 2 < nstep);
            issueV(1, (i + 1) << 5);
            if (pfP) loadP(RpA, (i + 2) << 5);
            domfma(0);
            if (pfP) WAIT_VM(4); else WAIT_VM(2);   // RpB landed
            writeA(1, RpB, (i + 1) << 5);
            if (pfP) WAIT_VM(2); else WAIT_VM(0);   // V(i+1) landed (RpA may fly)
            WAIT_LGKM0();                            // my As writes visible
            BARRIER();
        }
        // ---- odd step i+1: compute buf1; build buf0 from RpA; prefetch P(i+3)->RpB
        {
            const bool pfV = (i + 2 < nstep);
            const bool pfP = (i + 3 < nstep);
            if (pfV) issueV(0, (i + 2) << 5);
            if (pfP) loadP(RpB, (i + 3) << 5);
            domfma(1);
            if (pfV) {
                if (pfP) WAIT_VM(4); else WAIT_VM(2);   // RpA landed
                writeA(0, RpA, (i + 2) << 5);
                if (pfP) WAIT_VM(2); else WAIT_VM(0);   // V(i+2) landed
                WAIT_LGKM0();
            }
            BARRIER();
        }
    }

#pragma unroll
    for (int i = 0; i < 4; ++i)
#pragma unroll
        for (int r2 = 0; r2 < 4; ++r2) {
            const int row = q0 + (wr + i) * 16 + lq * 4 + r2;
#pragma unroll
            for (int j = 0; j < 4; ++j)
                Ob[(size_t)row * Dd + d0 + (wc + j) * 16 + lr] = acc[i][j][r2];
        }
}

}  // namespace

extern "C" void kernel_launch(void* const* d_in, const int* in_sizes, int n_in,
                              void* d_out, int out_size, void* d_ws, size_t ws_size,
                              hipStream_t stream)
{
    const float* X  = (const float*)d_in[0];
    const float* Wq = (const float*)d_in[1];
    const float* Wk = (const float*)d_in[2];
    const float* Wv = (const float*)d_in[3];

    char* ws = (char*)d_ws;
    const size_t MB = 1024 * 1024;
    _Float16* Xhi  = (_Float16*)ws;
    _Float16* Xlo  = (_Float16*)(ws + 16 * MB);
    _Float16* Wqh  = (_Float16*)(ws + 32 * MB);
    _Float16* Wql  = (_Float16*)(ws + 34 * MB);
    _Float16* Wkh  = (_Float16*)(ws + 36 * MB);
    _Float16* Wkl  = (_Float16*)(ws + 38 * MB);
    _Float16* WvTh = (_Float16*)(ws + 40 * MB);
    _Float16* GTh  = (_Float16*)(ws + 44 * MB);
    _Float16* GTl  = (_Float16*)(ws + 46 * MB);
    _Float16* Thi  = (_Float16*)(ws + 48 * MB);
    _Float16* Tlo  = (_Float16*)(ws + 64 * MB);
    _Float16* Vt   = (_Float16*)(ws + 80 * MB);
    _Float16* Pp   = (_Float16*)(ws + 112 * MB);      // 32 MB f16 P'
    float*    Mb   = (float*)(ws + 176 * MB);
    float*    Lb   = Mb + (size_t)Bb * Tt;
    float*    Pm   = Lb + (size_t)Bb * Tt;
    float*    Pl   = Pm + (size_t)Bb * NCH * Tt;
    float*    Out  = (float*)d_out;

    convert_all_kernel<<<10496, 256, 0, stream>>>(X, Wq, Wk, Wv, Xhi, Xlo,
                                                  Wqh, Wql, Wkh, Wkl, WvTh);
    gt_kernel<<<dim3(16, 16), 256, 0, stream>>>(Wkh, Wkl, Wqh, Wql, GTh, GTl);
    tv_kernel<<<dim3(1024), 256, 0, stream>>>(Xhi, Xlo, GTh, GTl, WvTh, Thi, Tlo, Vt);
    scores_mfma_kernel<<<dim3(544), 256, 0, stream>>>(Thi, Tlo, Xhi, Xlo, Pp, Pm, Pl);
    colstats_merge_kernel<<<dim3(Tt / 256, Bb), 256, 0, stream>>>(Pm, Pl, Mb, Lb);
    context_mfma_kernel<<<dim3(512), 256, 0, stream>>>(Pp, Pm, Mb, Lb, Vt, Out);
}

// Round 12
// 390.545 us; speedup vs baseline: 1.3101x; 1.0152x over previous
//
#include <hip/hip_runtime.h>
#include <math.h>

typedef _Float16 half4 __attribute__((ext_vector_type(4)));
typedef _Float16 half8 __attribute__((ext_vector_type(8)));
typedef float f32x4 __attribute__((ext_vector_type(4)));

#define GLD16(gptr, lptr)                                                     \
    __builtin_amdgcn_global_load_lds(                                         \
        (const __attribute__((address_space(1))) unsigned int*)(gptr),        \
        (__attribute__((address_space(3))) unsigned int*)(lptr), 16, 0, 0)

#define WAIT_VM(N) asm volatile("s_waitcnt vmcnt(" #N ")" ::: "memory")
#define WAIT_LGKM0() asm volatile("s_waitcnt lgkmcnt(0)" ::: "memory")
#define BARRIER()  __builtin_amdgcn_s_barrier()
#define SCHED_FENCE() __builtin_amdgcn_sched_barrier(0)

namespace {

constexpr int Bb = 4;
constexpr int Tt = 2048;
constexpr int Dd = 1024;
constexpr int BT = Bb * Tt;   // 8192
constexpr int NCH = 16;       // stats chunks = 128-row tiles

__device__ inline _Float16 f2h(float f) { return (_Float16)f; }

// ---------------------------------------------------------------------------
// FUSED converts: X -> Xhi/Xlo ; Wq,Wk -> hi/lo ; Wv -> WvT hi.
// ---------------------------------------------------------------------------
__global__ __launch_bounds__(256) void convert_all_kernel(
    const float* __restrict__ X,  const float* __restrict__ Wq,
    const float* __restrict__ Wk, const float* __restrict__ Wv,
    _Float16* __restrict__ Xhi, _Float16* __restrict__ Xlo,
    _Float16* __restrict__ Wqh, _Float16* __restrict__ Wql,
    _Float16* __restrict__ Wkh, _Float16* __restrict__ Wkl,
    _Float16* __restrict__ WvTh)
{
    __shared__ float tile[64][65];
    const int f = blockIdx.x;
    if (f < 8192) {
        const int idx = f * 1024 + threadIdx.x * 4;
        const float4 v = *(const float4*)(X + idx);
        const float a[4] = {v.x, v.y, v.z, v.w};
        half4 h, l;
#pragma unroll
        for (int i = 0; i < 4; ++i) {
            h[i] = f2h(a[i]);
            l[i] = f2h(a[i] - (float)h[i]);
        }
        *(half4*)(Xhi + idx) = h;
        *(half4*)(Xlo + idx) = l;
    } else if (f < 10240) {
        const int g = f - 8192;
        const int mat = g >> 10;
        const float* W = mat ? Wk : Wq;
        _Float16* Hh = mat ? Wkh : Wqh;
        _Float16* Ll = mat ? Wkl : Wql;
        const int idx = (g & 1023) * 1024 + threadIdx.x * 4;
        const float4 v = *(const float4*)(W + idx);
        const float a[4] = {v.x, v.y, v.z, v.w};
        half4 h, l;
#pragma unroll
        for (int i = 0; i < 4; ++i) {
            h[i] = f2h(a[i]);
            l[i] = f2h(a[i] - (float)h[i]);
        }
        *(half4*)(Hh + idx) = h;
        *(half4*)(Ll + idx) = l;
    } else {
        const int g = f - 10240;
        const int n0 = (g & 15) * 64, k0 = (g >> 4) * 64;
        const int tx = threadIdx.x & 63, ty = threadIdx.x >> 6;
#pragma unroll
        for (int i = 0; i < 16; ++i)
            tile[ty + i * 4][tx] = Wv[(size_t)(k0 + ty + i * 4) * Dd + n0 + tx];
        __syncthreads();
#pragma unroll
        for (int i = 0; i < 16; ++i) {
            const float v = tile[tx][ty + i * 4];
            WvTh[(size_t)(n0 + ty + i * 4) * Dd + k0 + tx] = f2h(v);
        }
    }
}

// ---------------------------------------------------------------------------
// GT[s][r] = sum_a Wk[s][a] * Wq[r][a]   (counted-vmcnt pipeline)
// ---------------------------------------------------------------------------
__global__ __launch_bounds__(256) void gt_kernel(
    const _Float16* __restrict__ Wkh, const _Float16* __restrict__ Wkl,
    const _Float16* __restrict__ Wqh, const _Float16* __restrict__ Wql,
    _Float16* __restrict__ GTh, _Float16* __restrict__ GTl)
{
    __shared__ _Float16 Ahl[2][2][4][512];
    __shared__ _Float16 Bhl[2][2][4][512];

    const int n0 = blockIdx.x * 64;
    const int m0 = blockIdx.y * 64;
    const int tid = threadIdx.x;
    const int w = tid >> 6, lane = tid & 63;
    const int lr = lane & 15, lq = lane >> 4;
    const int wi = (w >> 1) * 2, wj = (w & 1) * 2;

    f32x4 acc[2][2];
#pragma unroll
    for (int i = 0; i < 2; ++i)
#pragma unroll
        for (int j = 0; j < 2; ++j)
#pragma unroll
            for (int c = 0; c < 4; ++c) acc[i][j][c] = 0.f;

    auto stage = [&](int bf, int kk) {
        const int s = w;
        const size_t ar = (size_t)(m0 + s * 16 + lr) * Dd + kk + lq * 8;
        const size_t br = (size_t)(n0 + s * 16 + lr) * Dd + kk + lq * 8;
        GLD16(Wkh + ar, &Ahl[bf][0][s][0]);
        GLD16(Wkl + ar, &Ahl[bf][1][s][0]);
        GLD16(Wqh + br, &Bhl[bf][0][s][0]);
        GLD16(Wql + br, &Bhl[bf][1][s][0]);
    };

    stage(0, 0);
    int ib = 0;
    for (int step = 0; step < 32; ++step, ib ^= 1) {
        if (step < 31) {
            stage(ib ^ 1, (step + 1) << 5);
            WAIT_VM(4);
        } else {
            WAIT_VM(0);
        }
        BARRIER();
        SCHED_FENCE();
        half8 ah[2], al[2], bh[2], bl[2];
#pragma unroll
        for (int i = 0; i < 2; ++i) {
            ah[i] = *(const half8*)&Ahl[ib][0][wi + i][lane * 8];
            al[i] = *(const half8*)&Ahl[ib][1][wi + i][lane * 8];
        }
#pragma unroll
        for (int j = 0; j < 2; ++j) {
            bh[j] = *(const half8*)&Bhl[ib][0][wj + j][lane * 8];
            bl[j] = *(const half8*)&Bhl[ib][1][wj + j][lane * 8];
        }
#pragma unroll
        for (int i = 0; i < 2; ++i)
#pragma unroll
            for (int j = 0; j < 2; ++j) {
                acc[i][j] = __builtin_amdgcn_mfma_f32_16x16x32_f16(ah[i], bh[j], acc[i][j], 0, 0, 0);
                acc[i][j] = __builtin_amdgcn_mfma_f32_16x16x32_f16(ah[i], bl[j], acc[i][j], 0, 0, 0);
                acc[i][j] = __builtin_amdgcn_mfma_f32_16x16x32_f16(al[i], bh[j], acc[i][j], 0, 0, 0);
            }
        BARRIER();
    }

#pragma unroll
    for (int i = 0; i < 2; ++i)
#pragma unroll
        for (int r = 0; r < 4; ++r) {
            const int row = m0 + (wi + i) * 16 + lq * 4 + r;
#pragma unroll
            for (int j = 0; j < 2; ++j) {
                const int col = n0 + (wj + j) * 16 + lr;
                const float v = acc[i][j][r];
                const _Float16 h = f2h(v);
                GTh[(size_t)row * Dd + col] = h;
                GTl[(size_t)row * Dd + col] = f2h(v - (float)h);
            }
        }
}

// ---------------------------------------------------------------------------
// FUSED  T = X*G (3-product hi/lo)  +  V = X*Wv (single product).
// ROLE-BALANCED mapping (round-8, measured win). v-role epilogue writes Vt.
// ---------------------------------------------------------------------------
__global__ __launch_bounds__(256, 2) void tv_kernel(
    const _Float16* __restrict__ Xhi, const _Float16* __restrict__ Xlo,
    const _Float16* __restrict__ GTh, const _Float16* __restrict__ GTl,
    const _Float16* __restrict__ WvTh,
    _Float16* __restrict__ Thi, _Float16* __restrict__ Tlo,
    _Float16* __restrict__ Vt)
{
    __shared__ _Float16 smem[32768];   // 64 KB: staging dbuf; v-role epilogue scratch
    auto A_ = [&](int bf, int hl, int s) -> _Float16* {
        return smem + ((bf * 2 + hl) * 8 + s) * 512;
    };
    auto B_ = [&](int bf, int hl, int s) -> _Float16* {
        return smem + 16384 + ((bf * 2 + hl) * 8 + s) * 512;
    };

    const int f   = blockIdx.x;           // 0..1023
    const int xcd = f & 7;
    const int c   = (f >> 3) & 31;        // CU within XCD (assumed)
    const int p   = f >> 8;               // resident slot (assumed)
    const int mb  = xcd * 8 + (c & 7);    // m-panel 0..63
    const int sub = p * 4 + (c >> 3);     // 0..15; p<2 -> t-role
    const int m0 = mb * 128;
    const int n0 = (sub & 7) * 128;

    const int tid = threadIdx.x;
    const int w = tid >> 6, lane = tid & 63;
    const int lr = lane & 15, lq = lane >> 4;
    const int wr = (w >> 1) * 4, wc = (w & 1) * 4;

    f32x4 acc[4][4];
#pragma unroll
    for (int i = 0; i < 4; ++i)
#pragma unroll
        for (int j = 0; j < 4; ++j)
#pragma unroll
            for (int c2 = 0; c2 < 4; ++c2) acc[i][j][c2] = 0.f;

    if (sub < 8) {
        // ----- t-role: 3-product hi/lo -----
        auto stage = [&](int bf, int kk) {
#pragma unroll
            for (int s2 = 0; s2 < 2; ++s2) {
                const int s = w * 2 + s2;
                const size_t ar = (size_t)(m0 + s * 16 + lr) * Dd + kk + lq * 8;
                const size_t br = (size_t)(n0 + s * 16 + lr) * Dd + kk + lq * 8;
                GLD16(Xhi + ar, A_(bf, 0, s));
                GLD16(Xlo + ar, A_(bf, 1, s));
                GLD16(GTh + br, B_(bf, 0, s));
                GLD16(GTl + br, B_(bf, 1, s));
            }
        };
        stage(0, 0);
        int ib = 0;
        for (int step = 0; step < 32; ++step, ib ^= 1) {
            if (step < 31) {
                stage(ib ^ 1, (step + 1) << 5);
                WAIT_VM(8);
            } else {
                WAIT_VM(0);
            }
            BARRIER();
            SCHED_FENCE();
            half8 ah[4], al[4], bh[4], bl[4];
#pragma unroll
            for (int i = 0; i < 4; ++i) {
                ah[i] = *(const half8*)(A_(ib, 0, wr + i) + lane * 8);
                al[i] = *(const half8*)(A_(ib, 1, wr + i) + lane * 8);
            }
#pragma unroll
            for (int j = 0; j < 4; ++j) {
                bh[j] = *(const half8*)(B_(ib, 0, wc + j) + lane * 8);
                bl[j] = *(const half8*)(B_(ib, 1, wc + j) + lane * 8);
            }
#pragma unroll
            for (int i = 0; i < 4; ++i)
#pragma unroll
                for (int j = 0; j < 4; ++j) {
                    acc[i][j] = __builtin_amdgcn_mfma_f32_16x16x32_f16(ah[i], bh[j], acc[i][j], 0, 0, 0);
                    acc[i][j] = __builtin_amdgcn_mfma_f32_16x16x32_f16(ah[i], bl[j], acc[i][j], 0, 0, 0);
                    acc[i][j] = __builtin_amdgcn_mfma_f32_16x16x32_f16(al[i], bh[j], acc[i][j], 0, 0, 0);
                }
            BARRIER();
        }
#pragma unroll
        for (int i = 0; i < 4; ++i)
#pragma unroll
            for (int r = 0; r < 4; ++r) {
                const int row = m0 + (wr + i) * 16 + lq * 4 + r;
#pragma unroll
                for (int j = 0; j < 4; ++j) {
                    const int col = n0 + (wc + j) * 16 + lr;
                    const float v = acc[i][j][r];
                    const _Float16 h = f2h(v);
                    Thi[(size_t)row * Dd + col] = h;
                    Tlo[(size_t)row * Dd + col] = f2h(v - (float)h);
                }
            }
    } else {
        // ----- v-role: single product -----
        auto stage = [&](int bf, int kk) {
#pragma unroll
            for (int s2 = 0; s2 < 2; ++s2) {
                const int s = w * 2 + s2;
                GLD16(Xhi + (size_t)(m0 + s * 16 + lr) * Dd + kk + lq * 8, A_(bf, 0, s));
                GLD16(WvTh + (size_t)(n0 + s * 16 + lr) * Dd + kk + lq * 8, B_(bf, 0, s));
            }
        };
        stage(0, 0);
        int ib = 0;
        for (int step = 0; step < 32; ++step, ib ^= 1) {
            if (step < 31) {
                stage(ib ^ 1, (step + 1) << 5);
                WAIT_VM(4);
            } else {
                WAIT_VM(0);
            }
            BARRIER();
            SCHED_FENCE();
            half8 a[4], b2[4];
#pragma unroll
            for (int i = 0; i < 4; ++i) a[i] = *(const half8*)(A_(ib, 0, wr + i) + lane * 8);
#pragma unroll
            for (int j = 0; j < 4; ++j) b2[j] = *(const half8*)(B_(ib, 0, wc + j) + lane * 8);
#pragma unroll
            for (int i = 0; i < 4; ++i)
#pragma unroll
                for (int j = 0; j < 4; ++j)
                    acc[i][j] = __builtin_amdgcn_mfma_f32_16x16x32_f16(a[i], b2[j], acc[i][j], 0, 0, 0);
            BARRIER();
        }
        // ----- epilogue: write Vt[b][d][t] (pure transpose) via LDS -----
        __syncthreads();
#pragma unroll
        for (int i = 0; i < 4; ++i)
#pragma unroll
            for (int r2 = 0; r2 < 4; ++r2) {
                const int rloc = (wr + i) * 16 + lq * 4 + r2;   // local t-row
#pragma unroll
                for (int j = 0; j < 4; ++j) {
                    const int cloc = (wc + j) * 16 + lr;        // local d-col
                    smem[cloc * 136 + rloc] = f2h(acc[i][j][r2]);
                }
            }
        __syncthreads();
        const int b2i = m0 >> 11;            // batch (panels never straddle)
        const int t0  = m0 & 2047;
        const int dloc = tid >> 1, tl = (tid & 1) * 64;
        _Float16* vp = Vt + (size_t)b2i * Dd * Tt + (size_t)(n0 + dloc) * Tt + t0 + tl;
#pragma unroll
        for (int e = 0; e < 8; ++e)
            *(half8*)(vp + e * 8) = *(const half8*)&smem[dloc * 136 + tl + e * 8];
    }
}

// ---------------------------------------------------------------------------
// scores + FUSED column stats + P' write.  P' = f16(exp(Sf - chunkmax)).
// 512-THREAD variant: 8 waves/block, each wave 2x4 frags -> 16 waves/CU
// (4/SIMD) at the same 64 KB dbuf + counted-vmcnt schedule.  Tests whether
// scores is latency-bound (TLP doubling wins) vs LDS-read-bound (+50% reads).
// Staging: wave w stages row-group s=w for all 4 arrays (4 GLD16/thread).
// ---------------------------------------------------------------------------
__global__ __launch_bounds__(512, 4) void scores_mfma_kernel(
    const _Float16* __restrict__ Thi, const _Float16* __restrict__ Tlo,
    const _Float16* __restrict__ Xhi, const _Float16* __restrict__ Xlo,
    _Float16* __restrict__ Pp, float* __restrict__ Pm, float* __restrict__ Pl)
{
    const int f  = blockIdx.x;                // 0..543
    const int fp = (f & 7) * 68 + (f >> 3);   // chunked bijective
    const int b = fp / 136;
    const int t = fp - b * 136;
    int byi = (int)((sqrtf(8.f * t + 1.f) - 1.f) * 0.5f);
    if ((byi + 1) * (byi + 2) / 2 <= t) ++byi;
    if (byi * (byi + 1) / 2 > t) --byi;
    const int bxi = t - byi * (byi + 1) / 2;
    const int j0 = bxi * 128, q0 = byi * 128;
    _Float16* Pb = Pp + (size_t)b * Tt * Tt;

    __shared__ _Float16 Ahl[2][2][8][512];    // 32 KB
    __shared__ _Float16 Bhl[2][2][8][512];    // 32 KB
    const _Float16* Th = Thi + (size_t)b * Tt * Dd;
    const _Float16* Tl = Tlo + (size_t)b * Tt * Dd;
    const _Float16* Xh = Xhi + (size_t)b * Tt * Dd;
    const _Float16* Xl = Xlo + (size_t)b * Tt * Dd;

    const int tid = threadIdx.x;              // 0..511
    const int w = tid >> 6, lane = tid & 63;  // w: 0..7
    const int lr = lane & 15, lq = lane >> 4;
    const int wr = (w >> 1) * 2;              // frag-row base (2 rows/wave)
    const int wc = (w & 1) * 4;               // frag-col base (4 cols/wave)

    f32x4 acc[2][4];
#pragma unroll
    for (int i = 0; i < 2; ++i)
#pragma unroll
        for (int j = 0; j < 4; ++j)
#pragma unroll
            for (int c = 0; c < 4; ++c) acc[i][j][c] = 0.f;

    auto stage = [&](int bf, int kk) {
        const size_t ar = (size_t)(q0 + w * 16 + lr) * Dd + kk + lq * 8;
        const size_t br = (size_t)(j0 + w * 16 + lr) * Dd + kk + lq * 8;
        GLD16(Th + ar, &Ahl[bf][0][w][0]);
        GLD16(Tl + ar, &Ahl[bf][1][w][0]);
        GLD16(Xh + br, &Bhl[bf][0][w][0]);
        GLD16(Xl + br, &Bhl[bf][1][w][0]);
    };

    stage(0, 0);
    int ib = 0;
    for (int step = 0; step < 32; ++step, ib ^= 1) {
        if (step < 31) {
            stage(ib ^ 1, (step + 1) << 5);
            WAIT_VM(4);
        } else {
            WAIT_VM(0);
        }
        BARRIER();
        SCHED_FENCE();
        half8 ah[2], al[2], bh[4], bl[4];
#pragma unroll
        for (int i = 0; i < 2; ++i) {
            ah[i] = *(const half8*)&Ahl[ib][0][wr + i][lane * 8];
            al[i] = *(const half8*)&Ahl[ib][1][wr + i][lane * 8];
        }
#pragma unroll
        for (int j = 0; j < 4; ++j) {
            bh[j] = *(const half8*)&Bhl[ib][0][wc + j][lane * 8];
            bl[j] = *(const half8*)&Bhl[ib][1][wc + j][lane * 8];
        }
#pragma unroll
        for (int i = 0; i < 2; ++i)
#pragma unroll
            for (int j = 0; j < 4; ++j) {
                acc[i][j] = __builtin_amdgcn_mfma_f32_16x16x32_f16(ah[i], bh[j], acc[i][j], 0, 0, 0);
                acc[i][j] = __builtin_amdgcn_mfma_f32_16x16x32_f16(ah[i], bl[j], acc[i][j], 0, 0, 0);
                acc[i][j] = __builtin_amdgcn_mfma_f32_16x16x32_f16(al[i], bh[j], acc[i][j], 0, 0, 0);
            }
        BARRIER();
    }

    // masked + floored values in registers
    float sv[2][4][4];
#pragma unroll
    for (int i = 0; i < 2; ++i)
#pragma unroll
        for (int r = 0; r < 4; ++r) {
            const int q = q0 + (wr + i) * 16 + lq * 4 + r;
#pragma unroll
            for (int j = 0; j < 4; ++j) {
                const int jg = j0 + (wc + j) * 16 + lr;
                sv[i][j][r] = (jg <= q) ? floorf(acc[i][j][r] * 0.03125f) : -INFINITY;
            }
        }

    // per-column stats + P' write (reuse staging LDS: 32x128 partials + colmax)
    float* red  = (float*)&Ahl[0][0][0][0];   // [32][128] = 16 KB (fits in Ahl)
    float* colm = red + 4096;                 // [128]
    __syncthreads();
    for (int e = tid; e < 4096; e += 512) red[e] = -INFINITY;
    __syncthreads();
    const int rowidx = (w * 4 + lq) * 128;    // rows 0..31
#pragma unroll
    for (int j = 0; j < 4; ++j) {
        const int c = (wc + j) * 16 + lr;
        float lm = -INFINITY;
#pragma unroll
        for (int i = 0; i < 2; ++i)
#pragma unroll
            for (int r = 0; r < 4; ++r) lm = fmaxf(lm, sv[i][j][r]);
        red[rowidx + c] = lm;
    }
    __syncthreads();
    if (tid < 128) {
        float m = -INFINITY;
#pragma unroll
        for (int e = 0; e < 32; ++e) m = fmaxf(m, red[e * 128 + tid]);
        colm[tid] = m;
    }
    __syncthreads();
    float ls[4];
#pragma unroll
    for (int j = 0; j < 4; ++j) {
        const int c = (wc + j) * 16 + lr;
        const int jg = j0 + c;
        const float m = colm[c];
        float s = 0.f;
#pragma unroll
        for (int i = 0; i < 2; ++i)
#pragma unroll
            for (int r = 0; r < 4; ++r) {
                const float e = __expf(sv[i][j][r] - m);   // masked -> exp(-inf)=0
                s += e;
                const int q = q0 + (wr + i) * 16 + lq * 4 + r;
                Pb[(size_t)q * Tt + jg] = f2h(e);
            }
        ls[j] = s;
    }
    __syncthreads();
    for (int e = tid; e < 4096; e += 512) red[e] = 0.f;
    __syncthreads();
#pragma unroll
    for (int j = 0; j < 4; ++j) red[rowidx + (wc + j) * 16 + lr] = ls[j];
    __syncthreads();
    if (tid < 128) {
        float l = 0.f;
#pragma unroll
        for (int e = 0; e < 32; ++e) l += red[e * 128 + tid];
        const size_t o = ((size_t)b * NCH + byi) * Tt + j0 + tid;
        Pm[o] = colm[tid];
        Pl[o] = l;
    }
}

// ---------------------------------------------------------------------------
// merge NCH=16 partials per column -> m, 1/l  (index-predicated: c >= j>>7)
// ---------------------------------------------------------------------------
__global__ __launch_bounds__(256) void colstats_merge_kernel(
    const float* __restrict__ Pm, const float* __restrict__ Pl,
    float* __restrict__ Mb, float* __restrict__ Lb)
{
    const int j = blockIdx.x * 256 + threadIdx.x;
    const int b = blockIdx.y;
    const int jt = j >> 7;
    float m = -INFINITY, l = 0.f;
    for (int c = jt; c < NCH; ++c) {
        const size_t pidx = ((size_t)b * NCH + c) * Tt + j;
        const float mi = Pm[pidx];
        if (mi == -INFINITY) continue;
        const float li = Pl[pidx];
        if (mi > m) { l = l * __expf(m - mi) + li; m = mi; }
        else        { l += li * __expf(mi - m); }
    }
    Mb[(size_t)b * Tt + j] = m;
    Lb[(size_t)b * Tt + j] = (l > 0.f) ? 1.f / l : 0.f;
}

// ---------------------------------------------------------------------------
// context = P @ V.  A = P'(f16) * c_k, c_k precomputed in LDS.
// Pipelined (As dbuf + depth-2 P reg prefetch + counted vmcnt, 1 barrier/step).
// WORK-BALANCED mapping (round-8, measured win).
// ---------------------------------------------------------------------------
__global__ __launch_bounds__(256) void context_mfma_kernel(
    const _Float16* __restrict__ Pp, const float* __restrict__ Pm,
    const float* __restrict__ Mb, const float* __restrict__ Lb,
    const _Float16* __restrict__ Vt, float* __restrict__ Out)
{
    __shared__ _Float16 As[2][8][512];   // P tile f16 dbuf
    __shared__ _Float16 Bl[2][8][512];   // V dbuf
    __shared__ float cbuf[2048];         // per-k correction

    const int f   = blockIdx.x;              // 0..511
    const int xcd = f & 7;
    const int c   = (f >> 3) & 31;           // CU within XCD (assumed)
    const int p   = f >> 8;                  // resident slot (assumed, 0..1)
    const int b   = xcd >> 1;                // batch 0..3
    const int bx  = c & 7;
    const int base = ((xcd & 1) << 3) + ((c >> 3) << 1);   // 0,2,..,14
    const int by  = p ? (15 - base) : base;
    const int d0 = bx * 128;
    const int q0 = by * 128;
    const _Float16* Pb = Pp + (size_t)b * Tt * Tt;
    const float* Pmb = Pm + ((size_t)b * NCH + by) * Tt;
    const float* Mp = Mb + (size_t)b * Tt;
    const float* Lp = Lb + (size_t)b * Tt;
    const _Float16* Vb = Vt + (size_t)b * Dd * Tt;
    float* Ob = Out + (size_t)b * Tt * Dd;

    const int tid = threadIdx.x;
    const int w = tid >> 6, lane = tid & 63;
    const int lr = lane & 15, lq = lane >> 4;
    const int wr = (w >> 1) * 4, wc = (w & 1) * 4;
    const int kmax = q0 + 128;
    const int nstep = kmax >> 5;             // 4*(by+1): even, >= 4

    // precompute c[k] (one pass, cooperative)
    for (int k = tid; k < kmax; k += 256)
        cbuf[k] = __expf(Pmb[k] - Mp[k]) * Lp[k];

    f32x4 acc[4][4];
#pragma unroll
    for (int i = 0; i < 4; ++i)
#pragma unroll
        for (int j = 0; j < 4; ++j)
#pragma unroll
            for (int c2 = 0; c2 < 4; ++c2) acc[i][j][c2] = 0.f;

    half8 RpA[2], RpB[2];
    auto loadP = [&](half8 (&R)[2], int k0) {
#pragma unroll
        for (int s2 = 0; s2 < 2; ++s2) {
            const int s = w * 2 + s2;
            R[s2] = *(const half8*)(Pb + (size_t)(q0 + s * 16 + lr) * Tt + k0 + lq * 8);
        }
    };
    auto issueV = [&](int bf, int k0) {
#pragma unroll
        for (int s2 = 0; s2 < 2; ++s2) {
            const int s = w * 2 + s2;
            GLD16(Vb + (size_t)(d0 + s * 16 + lr) * Tt + k0 + lq * 8, &Bl[bf][s][0]);
        }
    };
    auto writeA = [&](int bf, half8 (&R)[2], int k0) {
        const float* cp = cbuf + k0 + lq * 8;
        float cv[8];
#pragma unroll
        for (int e = 0; e < 8; ++e) cv[e] = cp[e];
#pragma unroll
        for (int s2 = 0; s2 < 2; ++s2) {
            const int s = w * 2 + s2;
            half8 out;
#pragma unroll
            for (int e = 0; e < 8; ++e) out[e] = f2h((float)R[s2][e] * cv[e]);
            *(half8*)&As[bf][s][lane * 8] = out;
        }
    };
    auto domfma = [&](int bf) {
        half8 a[4], b2[4];
#pragma unroll
        for (int i = 0; i < 4; ++i) a[i] = *(const half8*)&As[bf][wr + i][lane * 8];
#pragma unroll
        for (int j = 0; j < 4; ++j) b2[j] = *(const half8*)&Bl[bf][wc + j][lane * 8];
#pragma unroll
        for (int i = 0; i < 4; ++i)
#pragma unroll
            for (int j = 0; j < 4; ++j)
                acc[i][j] = __builtin_amdgcn_mfma_f32_16x16x32_f16(a[i], b2[j], acc[i][j], 0, 0, 0);
    };

    __syncthreads();          // cbuf ready

    // prologue: V(0)->Bl0, P(0)->RpA, P(1)->RpB; build As0
    issueV(0, 0);
    loadP(RpA, 0);
    loadP(RpB, 32);
    WAIT_VM(2);               // V(0)+RpA landed (RpB still flying)
    writeA(0, RpA, 0);
    WAIT_LGKM0();
    BARRIER();

    for (int i = 0; i < nstep; i += 2) {
        // ---- even step i: compute buf0; build buf1 from RpB; prefetch P(i+2)->RpA
        {
            const bool pfP = (i + 2 < nstep);
            issueV(1, (i + 1) << 5);
            if (pfP) loadP(RpA, (i + 2) << 5);
            domfma(0);
            if (pfP) WAIT_VM(4); else WAIT_VM(2);   // RpB landed
            writeA(1, RpB, (i + 1) << 5);
            if (pfP) WAIT_VM(2); else WAIT_VM(0);   // V(i+1) landed (RpA may fly)
            WAIT_LGKM0();                            // my As writes visible
            BARRIER();
        }
        // ---- odd step i+1: compute buf1; build buf0 from RpA; prefetch P(i+3)->RpB
        {
            const bool pfV = (i + 2 < nstep);
            const bool pfP = (i + 3 < nstep);
            if (pfV) issueV(0, (i + 2) << 5);
            if (pfP) loadP(RpB, (i + 3) << 5);
            domfma(1);
            if (pfV) {
                if (pfP) WAIT_VM(4); else WAIT_VM(2);   // RpA landed
                writeA(0, RpA, (i + 2) << 5);
                if (pfP) WAIT_VM(2); else WAIT_VM(0);   // V(i+2) landed
                WAIT_LGKM0();
            }
            BARRIER();
        }
    }

#pragma unroll
    for (int i = 0; i < 4; ++i)
#pragma unroll
        for (int r2 = 0; r2 < 4; ++r2) {
            const int row = q0 + (wr + i) * 16 + lq * 4 + r2;
#pragma unroll
            for (int j = 0; j < 4; ++j)
                Ob[(size_t)row * Dd + d0 + (wc + j) * 16 + lr] = acc[i][j][r2];
        }
}

}  // namespace

extern "C" void kernel_launch(void* const* d_in, const int* in_sizes, int n_in,
                              void* d_out, int out_size, void* d_ws, size_t ws_size,
                              hipStream_t stream)
{
    const float* X  = (const float*)d_in[0];
    const float* Wq = (const float*)d_in[1];
    const float* Wk = (const float*)d_in[2];
    const float* Wv = (const float*)d_in[3];

    char* ws = (char*)d_ws;
    const size_t MB = 1024 * 1024;
    _Float16* Xhi  = (_Float16*)ws;
    _Float16* Xlo  = (_Float16*)(ws + 16 * MB);
    _Float16* Wqh  = (_Float16*)(ws + 32 * MB);
    _Float16* Wql  = (_Float16*)(ws + 34 * MB);
    _Float16* Wkh  = (_Float16*)(ws + 36 * MB);
    _Float16* Wkl  = (_Float16*)(ws + 38 * MB);
    _Float16* WvTh = (_Float16*)(ws + 40 * MB);
    _Float16* GTh  = (_Float16*)(ws + 44 * MB);
    _Float16* GTl  = (_Float16*)(ws + 46 * MB);
    _Float16* Thi  = (_Float16*)(ws + 48 * MB);
    _Float16* Tlo  = (_Float16*)(ws + 64 * MB);
    _Float16* Vt   = (_Float16*)(ws + 80 * MB);
    _Float16* Pp   = (_Float16*)(ws + 112 * MB);      // 32 MB f16 P'
    float*    Mb   = (float*)(ws + 176 * MB);
    float*    Lb   = Mb + (size_t)Bb * Tt;
    float*    Pm   = Lb + (size_t)Bb * Tt;
    float*    Pl   = Pm + (size_t)Bb * NCH * Tt;
    float*    Out  = (float*)d_out;

    convert_all_kernel<<<10496, 256, 0, stream>>>(X, Wq, Wk, Wv, Xhi, Xlo,
                                                  Wqh, Wql, Wkh, Wkl, WvTh);
    gt_kernel<<<dim3(16, 16), 256, 0, stream>>>(Wkh, Wkl, Wqh, Wql, GTh, GTl);
    tv_kernel<<<dim3(1024), 256, 0, stream>>>(Xhi, Xlo, GTh, GTl, WvTh, Thi, Tlo, Vt);
    scores_mfma_kernel<<<dim3(544), 512, 0, stream>>>(Thi, Tlo, Xhi, Xlo, Pp, Pm, Pl);
    colstats_merge_kernel<<<dim3(Tt / 256, Bb), 256, 0, stream>>>(Pm, Pl, Mb, Lb);
    context_mfma_kernel<<<dim3(512), 256, 0, stream>>>(Pp, Pm, Mb, Lb, Vt, Out);
}

// Round 13
// 387.836 us; speedup vs baseline: 1.3192x; 1.0070x over previous
//
#include <hip/hip_runtime.h>
#include <math.h>

typedef _Float16 half4 __attribute__((ext_vector_type(4)));
typedef _Float16 half8 __attribute__((ext_vector_type(8)));
typedef float f32x4 __attribute__((ext_vector_type(4)));

#define GLD16(gptr, lptr)                                                     \
    __builtin_amdgcn_global_load_lds(                                         \
        (const __attribute__((address_space(1))) unsigned int*)(gptr),        \
        (__attribute__((address_space(3))) unsigned int*)(lptr), 16, 0, 0)

#define WAIT_VM(N) asm volatile("s_waitcnt vmcnt(" #N ")" ::: "memory")
#define WAIT_LGKM0() asm volatile("s_waitcnt lgkmcnt(0)" ::: "memory")
#define BARRIER()  __builtin_amdgcn_s_barrier()
#define SCHED_FENCE() __builtin_amdgcn_sched_barrier(0)

namespace {

constexpr int Bb = 4;
constexpr int Tt = 2048;
constexpr int Dd = 1024;
constexpr int BT = Bb * Tt;   // 8192
constexpr int NCH = 16;       // stats chunks = 128-row tiles

__device__ inline _Float16 f2h(float f) { return (_Float16)f; }

// ---------------------------------------------------------------------------
// FUSED converts: X -> Xhi/Xlo ; Wq,Wk -> hi/lo ; Wv -> WvT hi.
// ---------------------------------------------------------------------------
__global__ __launch_bounds__(256) void convert_all_kernel(
    const float* __restrict__ X,  const float* __restrict__ Wq,
    const float* __restrict__ Wk, const float* __restrict__ Wv,
    _Float16* __restrict__ Xhi, _Float16* __restrict__ Xlo,
    _Float16* __restrict__ Wqh, _Float16* __restrict__ Wql,
    _Float16* __restrict__ Wkh, _Float16* __restrict__ Wkl,
    _Float16* __restrict__ WvTh)
{
    __shared__ float tile[64][65];
    const int f = blockIdx.x;
    if (f < 8192) {
        const int idx = f * 1024 + threadIdx.x * 4;
        const float4 v = *(const float4*)(X + idx);
        const float a[4] = {v.x, v.y, v.z, v.w};
        half4 h, l;
#pragma unroll
        for (int i = 0; i < 4; ++i) {
            h[i] = f2h(a[i]);
            l[i] = f2h(a[i] - (float)h[i]);
        }
        *(half4*)(Xhi + idx) = h;
        *(half4*)(Xlo + idx) = l;
    } else if (f < 10240) {
        const int g = f - 8192;
        const int mat = g >> 10;
        const float* W = mat ? Wk : Wq;
        _Float16* Hh = mat ? Wkh : Wqh;
        _Float16* Ll = mat ? Wkl : Wql;
        const int idx = (g & 1023) * 1024 + threadIdx.x * 4;
        const float4 v = *(const float4*)(W + idx);
        const float a[4] = {v.x, v.y, v.z, v.w};
        half4 h, l;
#pragma unroll
        for (int i = 0; i < 4; ++i) {
            h[i] = f2h(a[i]);
            l[i] = f2h(a[i] - (float)h[i]);
        }
        *(half4*)(Hh + idx) = h;
        *(half4*)(Ll + idx) = l;
    } else {
        const int g = f - 10240;
        const int n0 = (g & 15) * 64, k0 = (g >> 4) * 64;
        const int tx = threadIdx.x & 63, ty = threadIdx.x >> 6;
#pragma unroll
        for (int i = 0; i < 16; ++i)
            tile[ty + i * 4][tx] = Wv[(size_t)(k0 + ty + i * 4) * Dd + n0 + tx];
        __syncthreads();
#pragma unroll
        for (int i = 0; i < 16; ++i) {
            const float v = tile[tx][ty + i * 4];
            WvTh[(size_t)(n0 + ty + i * 4) * Dd + k0 + tx] = f2h(v);
        }
    }
}

// ---------------------------------------------------------------------------
// GT[s][r] = sum_a Wk[s][a] * Wq[r][a]   (counted-vmcnt pipeline)
// ---------------------------------------------------------------------------
__global__ __launch_bounds__(256) void gt_kernel(
    const _Float16* __restrict__ Wkh, const _Float16* __restrict__ Wkl,
    const _Float16* __restrict__ Wqh, const _Float16* __restrict__ Wql,
    _Float16* __restrict__ GTh, _Float16* __restrict__ GTl)
{
    __shared__ _Float16 Ahl[2][2][4][512];
    __shared__ _Float16 Bhl[2][2][4][512];

    const int n0 = blockIdx.x * 64;
    const int m0 = blockIdx.y * 64;
    const int tid = threadIdx.x;
    const int w = tid >> 6, lane = tid & 63;
    const int lr = lane & 15, lq = lane >> 4;
    const int wi = (w >> 1) * 2, wj = (w & 1) * 2;

    f32x4 acc[2][2];
#pragma unroll
    for (int i = 0; i < 2; ++i)
#pragma unroll
        for (int j = 0; j < 2; ++j)
#pragma unroll
            for (int c = 0; c < 4; ++c) acc[i][j][c] = 0.f;

    auto stage = [&](int bf, int kk) {
        const int s = w;
        const size_t ar = (size_t)(m0 + s * 16 + lr) * Dd + kk + lq * 8;
        const size_t br = (size_t)(n0 + s * 16 + lr) * Dd + kk + lq * 8;
        GLD16(Wkh + ar, &Ahl[bf][0][s][0]);
        GLD16(Wkl + ar, &Ahl[bf][1][s][0]);
        GLD16(Wqh + br, &Bhl[bf][0][s][0]);
        GLD16(Wql + br, &Bhl[bf][1][s][0]);
    };

    stage(0, 0);
    int ib = 0;
    for (int step = 0; step < 32; ++step, ib ^= 1) {
        if (step < 31) {
            stage(ib ^ 1, (step + 1) << 5);
            WAIT_VM(4);
        } else {
            WAIT_VM(0);
        }
        BARRIER();
        SCHED_FENCE();
        half8 ah[2], al[2], bh[2], bl[2];
#pragma unroll
        for (int i = 0; i < 2; ++i) {
            ah[i] = *(const half8*)&Ahl[ib][0][wi + i][lane * 8];
            al[i] = *(const half8*)&Ahl[ib][1][wi + i][lane * 8];
        }
#pragma unroll
        for (int j = 0; j < 2; ++j) {
            bh[j] = *(const half8*)&Bhl[ib][0][wj + j][lane * 8];
            bl[j] = *(const half8*)&Bhl[ib][1][wj + j][lane * 8];
        }
#pragma unroll
        for (int i = 0; i < 2; ++i)
#pragma unroll
            for (int j = 0; j < 2; ++j) {
                acc[i][j] = __builtin_amdgcn_mfma_f32_16x16x32_f16(ah[i], bh[j], acc[i][j], 0, 0, 0);
                acc[i][j] = __builtin_amdgcn_mfma_f32_16x16x32_f16(ah[i], bl[j], acc[i][j], 0, 0, 0);
                acc[i][j] = __builtin_amdgcn_mfma_f32_16x16x32_f16(al[i], bh[j], acc[i][j], 0, 0, 0);
            }
        BARRIER();
    }

#pragma unroll
    for (int i = 0; i < 2; ++i)
#pragma unroll
        for (int r = 0; r < 4; ++r) {
            const int row = m0 + (wi + i) * 16 + lq * 4 + r;
#pragma unroll
            for (int j = 0; j < 2; ++j) {
                const int col = n0 + (wj + j) * 16 + lr;
                const float v = acc[i][j][r];
                const _Float16 h = f2h(v);
                GTh[(size_t)row * Dd + col] = h;
                GTl[(size_t)row * Dd + col] = f2h(v - (float)h);
            }
        }
}

// ---------------------------------------------------------------------------
// FUSED  T = X*G (3-product hi/lo)  +  V = X*Wv (single product).
// 512-THREAD variant: 8 waves/block, each wave 2x4 frags -> 16 waves/CU at
// 2 blocks/CU (64 KB LDS).  ROLE-BALANCED mapping (round-8).  Wave w stages
// row-group s=w.  v-role epilogue writes Vt (pure transpose, re-indexed).
// ---------------------------------------------------------------------------
__global__ __launch_bounds__(512, 4) void tv_kernel(
    const _Float16* __restrict__ Xhi, const _Float16* __restrict__ Xlo,
    const _Float16* __restrict__ GTh, const _Float16* __restrict__ GTl,
    const _Float16* __restrict__ WvTh,
    _Float16* __restrict__ Thi, _Float16* __restrict__ Tlo,
    _Float16* __restrict__ Vt)
{
    __shared__ _Float16 smem[32768];   // 64 KB: staging dbuf; v-role epilogue scratch
    auto A_ = [&](int bf, int hl, int s) -> _Float16* {
        return smem + ((bf * 2 + hl) * 8 + s) * 512;
    };
    auto B_ = [&](int bf, int hl, int s) -> _Float16* {
        return smem + 16384 + ((bf * 2 + hl) * 8 + s) * 512;
    };

    const int f   = blockIdx.x;           // 0..1023
    const int xcd = f & 7;
    const int c   = (f >> 3) & 31;        // CU within XCD (assumed)
    const int p   = f >> 8;               // resident slot (assumed)
    const int mb  = xcd * 8 + (c & 7);    // m-panel 0..63
    const int sub = p * 4 + (c >> 3);     // 0..15; p<2 -> t-role
    const int m0 = mb * 128;
    const int n0 = (sub & 7) * 128;

    const int tid = threadIdx.x;          // 0..511
    const int w = tid >> 6, lane = tid & 63;   // w: 0..7
    const int lr = lane & 15, lq = lane >> 4;
    const int wr = (w >> 1) * 2;          // frag-row base (2 rows/wave)
    const int wc = (w & 1) * 4;           // frag-col base (4 cols/wave)

    f32x4 acc[2][4];
#pragma unroll
    for (int i = 0; i < 2; ++i)
#pragma unroll
        for (int j = 0; j < 4; ++j)
#pragma unroll
            for (int c2 = 0; c2 < 4; ++c2) acc[i][j][c2] = 0.f;

    if (sub < 8) {
        // ----- t-role: 3-product hi/lo -----
        auto stage = [&](int bf, int kk) {
            const size_t ar = (size_t)(m0 + w * 16 + lr) * Dd + kk + lq * 8;
            const size_t br = (size_t)(n0 + w * 16 + lr) * Dd + kk + lq * 8;
            GLD16(Xhi + ar, A_(bf, 0, w));
            GLD16(Xlo + ar, A_(bf, 1, w));
            GLD16(GTh + br, B_(bf, 0, w));
            GLD16(GTl + br, B_(bf, 1, w));
        };
        stage(0, 0);
        int ib = 0;
        for (int step = 0; step < 32; ++step, ib ^= 1) {
            if (step < 31) {
                stage(ib ^ 1, (step + 1) << 5);
                WAIT_VM(4);
            } else {
                WAIT_VM(0);
            }
            BARRIER();
            SCHED_FENCE();
            half8 ah[2], al[2], bh[4], bl[4];
#pragma unroll
            for (int i = 0; i < 2; ++i) {
                ah[i] = *(const half8*)(A_(ib, 0, wr + i) + lane * 8);
                al[i] = *(const half8*)(A_(ib, 1, wr + i) + lane * 8);
            }
#pragma unroll
            for (int j = 0; j < 4; ++j) {
                bh[j] = *(const half8*)(B_(ib, 0, wc + j) + lane * 8);
                bl[j] = *(const half8*)(B_(ib, 1, wc + j) + lane * 8);
            }
#pragma unroll
            for (int i = 0; i < 2; ++i)
#pragma unroll
                for (int j = 0; j < 4; ++j) {
                    acc[i][j] = __builtin_amdgcn_mfma_f32_16x16x32_f16(ah[i], bh[j], acc[i][j], 0, 0, 0);
                    acc[i][j] = __builtin_amdgcn_mfma_f32_16x16x32_f16(ah[i], bl[j], acc[i][j], 0, 0, 0);
                    acc[i][j] = __builtin_amdgcn_mfma_f32_16x16x32_f16(al[i], bh[j], acc[i][j], 0, 0, 0);
                }
            BARRIER();
        }
#pragma unroll
        for (int i = 0; i < 2; ++i)
#pragma unroll
            for (int r = 0; r < 4; ++r) {
                const int row = m0 + (wr + i) * 16 + lq * 4 + r;
#pragma unroll
                for (int j = 0; j < 4; ++j) {
                    const int col = n0 + (wc + j) * 16 + lr;
                    const float v = acc[i][j][r];
                    const _Float16 h = f2h(v);
                    Thi[(size_t)row * Dd + col] = h;
                    Tlo[(size_t)row * Dd + col] = f2h(v - (float)h);
                }
            }
    } else {
        // ----- v-role: single product -----
        auto stage = [&](int bf, int kk) {
            GLD16(Xhi + (size_t)(m0 + w * 16 + lr) * Dd + kk + lq * 8, A_(bf, 0, w));
            GLD16(WvTh + (size_t)(n0 + w * 16 + lr) * Dd + kk + lq * 8, B_(bf, 0, w));
        };
        stage(0, 0);
        int ib = 0;
        for (int step = 0; step < 32; ++step, ib ^= 1) {
            if (step < 31) {
                stage(ib ^ 1, (step + 1) << 5);
                WAIT_VM(2);
            } else {
                WAIT_VM(0);
            }
            BARRIER();
            SCHED_FENCE();
            half8 a[2], b2[4];
#pragma unroll
            for (int i = 0; i < 2; ++i) a[i] = *(const half8*)(A_(ib, 0, wr + i) + lane * 8);
#pragma unroll
            for (int j = 0; j < 4; ++j) b2[j] = *(const half8*)(B_(ib, 0, wc + j) + lane * 8);
#pragma unroll
            for (int i = 0; i < 2; ++i)
#pragma unroll
                for (int j = 0; j < 4; ++j)
                    acc[i][j] = __builtin_amdgcn_mfma_f32_16x16x32_f16(a[i], b2[j], acc[i][j], 0, 0, 0);
            BARRIER();
        }
        // ----- epilogue: write Vt[b][d][t] (pure transpose) via LDS -----
        __syncthreads();
#pragma unroll
        for (int i = 0; i < 2; ++i)
#pragma unroll
            for (int r2 = 0; r2 < 4; ++r2) {
                const int rloc = (wr + i) * 16 + lq * 4 + r2;   // local t-row
#pragma unroll
                for (int j = 0; j < 4; ++j) {
                    const int cloc = (wc + j) * 16 + lr;        // local d-col
                    smem[cloc * 136 + rloc] = f2h(acc[i][j][r2]);
                }
            }
        __syncthreads();
        const int b2i = m0 >> 11;            // batch (panels never straddle)
        const int t0  = m0 & 2047;
        const int dloc = tid >> 2, tl = (tid & 3) * 32;
        _Float16* vp = Vt + (size_t)b2i * Dd * Tt + (size_t)(n0 + dloc) * Tt + t0 + tl;
#pragma unroll
        for (int e = 0; e < 4; ++e)
            *(half8*)(vp + e * 8) = *(const half8*)&smem[dloc * 136 + tl + e * 8];
    }
}

// ---------------------------------------------------------------------------
// scores + FUSED column stats + P' write.  P' = f16(exp(Sf - chunkmax)).
// 512-THREAD variant (round-12, measured win).
// ---------------------------------------------------------------------------
__global__ __launch_bounds__(512, 4) void scores_mfma_kernel(
    const _Float16* __restrict__ Thi, const _Float16* __restrict__ Tlo,
    const _Float16* __restrict__ Xhi, const _Float16* __restrict__ Xlo,
    _Float16* __restrict__ Pp, float* __restrict__ Pm, float* __restrict__ Pl)
{
    const int f  = blockIdx.x;                // 0..543
    const int fp = (f & 7) * 68 + (f >> 3);   // chunked bijective
    const int b = fp / 136;
    const int t = fp - b * 136;
    int byi = (int)((sqrtf(8.f * t + 1.f) - 1.f) * 0.5f);
    if ((byi + 1) * (byi + 2) / 2 <= t) ++byi;
    if (byi * (byi + 1) / 2 > t) --byi;
    const int bxi = t - byi * (byi + 1) / 2;
    const int j0 = bxi * 128, q0 = byi * 128;
    _Float16* Pb = Pp + (size_t)b * Tt * Tt;

    __shared__ _Float16 Ahl[2][2][8][512];    // 32 KB
    __shared__ _Float16 Bhl[2][2][8][512];    // 32 KB
    const _Float16* Th = Thi + (size_t)b * Tt * Dd;
    const _Float16* Tl = Tlo + (size_t)b * Tt * Dd;
    const _Float16* Xh = Xhi + (size_t)b * Tt * Dd;
    const _Float16* Xl = Xlo + (size_t)b * Tt * Dd;

    const int tid = threadIdx.x;              // 0..511
    const int w = tid >> 6, lane = tid & 63;  // w: 0..7
    const int lr = lane & 15, lq = lane >> 4;
    const int wr = (w >> 1) * 2;              // frag-row base (2 rows/wave)
    const int wc = (w & 1) * 4;               // frag-col base (4 cols/wave)

    f32x4 acc[2][4];
#pragma unroll
    for (int i = 0; i < 2; ++i)
#pragma unroll
        for (int j = 0; j < 4; ++j)
#pragma unroll
            for (int c = 0; c < 4; ++c) acc[i][j][c] = 0.f;

    auto stage = [&](int bf, int kk) {
        const size_t ar = (size_t)(q0 + w * 16 + lr) * Dd + kk + lq * 8;
        const size_t br = (size_t)(j0 + w * 16 + lr) * Dd + kk + lq * 8;
        GLD16(Th + ar, &Ahl[bf][0][w][0]);
        GLD16(Tl + ar, &Ahl[bf][1][w][0]);
        GLD16(Xh + br, &Bhl[bf][0][w][0]);
        GLD16(Xl + br, &Bhl[bf][1][w][0]);
    };

    stage(0, 0);
    int ib = 0;
    for (int step = 0; step < 32; ++step, ib ^= 1) {
        if (step < 31) {
            stage(ib ^ 1, (step + 1) << 5);
            WAIT_VM(4);
        } else {
            WAIT_VM(0);
        }
        BARRIER();
        SCHED_FENCE();
        half8 ah[2], al[2], bh[4], bl[4];
#pragma unroll
        for (int i = 0; i < 2; ++i) {
            ah[i] = *(const half8*)&Ahl[ib][0][wr + i][lane * 8];
            al[i] = *(const half8*)&Ahl[ib][1][wr + i][lane * 8];
        }
#pragma unroll
        for (int j = 0; j < 4; ++j) {
            bh[j] = *(const half8*)&Bhl[ib][0][wc + j][lane * 8];
            bl[j] = *(const half8*)&Bhl[ib][1][wc + j][lane * 8];
        }
#pragma unroll
        for (int i = 0; i < 2; ++i)
#pragma unroll
            for (int j = 0; j < 4; ++j) {
                acc[i][j] = __builtin_amdgcn_mfma_f32_16x16x32_f16(ah[i], bh[j], acc[i][j], 0, 0, 0);
                acc[i][j] = __builtin_amdgcn_mfma_f32_16x16x32_f16(ah[i], bl[j], acc[i][j], 0, 0, 0);
                acc[i][j] = __builtin_amdgcn_mfma_f32_16x16x32_f16(al[i], bh[j], acc[i][j], 0, 0, 0);
            }
        BARRIER();
    }

    // masked + floored values in registers
    float sv[2][4][4];
#pragma unroll
    for (int i = 0; i < 2; ++i)
#pragma unroll
        for (int r = 0; r < 4; ++r) {
            const int q = q0 + (wr + i) * 16 + lq * 4 + r;
#pragma unroll
            for (int j = 0; j < 4; ++j) {
                const int jg = j0 + (wc + j) * 16 + lr;
                sv[i][j][r] = (jg <= q) ? floorf(acc[i][j][r] * 0.03125f) : -INFINITY;
            }
        }

    // per-column stats + P' write (reuse staging LDS: 32x128 partials + colmax)
    float* red  = (float*)&Ahl[0][0][0][0];   // [32][128]
    float* colm = red + 4096;                 // [128]
    __syncthreads();
    for (int e = tid; e < 4096; e += 512) red[e] = -INFINITY;
    __syncthreads();
    const int rowidx = (w * 4 + lq) * 128;    // rows 0..31
#pragma unroll
    for (int j = 0; j < 4; ++j) {
        const int c = (wc + j) * 16 + lr;
        float lm = -INFINITY;
#pragma unroll
        for (int i = 0; i < 2; ++i)
#pragma unroll
            for (int r = 0; r < 4; ++r) lm = fmaxf(lm, sv[i][j][r]);
        red[rowidx + c] = lm;
    }
    __syncthreads();
    if (tid < 128) {
        float m = -INFINITY;
#pragma unroll
        for (int e = 0; e < 32; ++e) m = fmaxf(m, red[e * 128 + tid]);
        colm[tid] = m;
    }
    __syncthreads();
    float ls[4];
#pragma unroll
    for (int j = 0; j < 4; ++j) {
        const int c = (wc + j) * 16 + lr;
        const int jg = j0 + c;
        const float m = colm[c];
        float s = 0.f;
#pragma unroll
        for (int i = 0; i < 2; ++i)
#pragma unroll
            for (int r = 0; r < 4; ++r) {
                const float e = __expf(sv[i][j][r] - m);   // masked -> exp(-inf)=0
                s += e;
                const int q = q0 + (wr + i) * 16 + lq * 4 + r;
                Pb[(size_t)q * Tt + jg] = f2h(e);
            }
        ls[j] = s;
    }
    __syncthreads();
    for (int e = tid; e < 4096; e += 512) red[e] = 0.f;
    __syncthreads();
#pragma unroll
    for (int j = 0; j < 4; ++j) red[rowidx + (wc + j) * 16 + lr] = ls[j];
    __syncthreads();
    if (tid < 128) {
        float l = 0.f;
#pragma unroll
        for (int e = 0; e < 32; ++e) l += red[e * 128 + tid];
        const size_t o = ((size_t)b * NCH + byi) * Tt + j0 + tid;
        Pm[o] = colm[tid];
        Pl[o] = l;
    }
}

// ---------------------------------------------------------------------------
// merge NCH=16 partials per column -> m, 1/l  (index-predicated: c >= j>>7)
// ---------------------------------------------------------------------------
__global__ __launch_bounds__(256) void colstats_merge_kernel(
    const float* __restrict__ Pm, const float* __restrict__ Pl,
    float* __restrict__ Mb, float* __restrict__ Lb)
{
    const int j = blockIdx.x * 256 + threadIdx.x;
    const int b = blockIdx.y;
    const int jt = j >> 7;
    float m = -INFINITY, l = 0.f;
    for (int c = jt; c < NCH; ++c) {
        const size_t pidx = ((size_t)b * NCH + c) * Tt + j;
        const float mi = Pm[pidx];
        if (mi == -INFINITY) continue;
        const float li = Pl[pidx];
        if (mi > m) { l = l * __expf(m - mi) + li; m = mi; }
        else        { l += li * __expf(mi - m); }
    }
    Mb[(size_t)b * Tt + j] = m;
    Lb[(size_t)b * Tt + j] = (l > 0.f) ? 1.f / l : 0.f;
}

// ---------------------------------------------------------------------------
// context = P @ V.  A = P'(f16) * c_k, c_k precomputed in LDS.
// Pipelined (As dbuf + depth-2 P reg prefetch + counted vmcnt, 1 barrier/step).
// WORK-BALANCED mapping (round-8, measured win).
// ---------------------------------------------------------------------------
__global__ __launch_bounds__(256) void context_mfma_kernel(
    const _Float16* __restrict__ Pp, const float* __restrict__ Pm,
    const float* __restrict__ Mb, const float* __restrict__ Lb,
    const _Float16* __restrict__ Vt, float* __restrict__ Out)
{
    __shared__ _Float16 As[2][8][512];   // P tile f16 dbuf
    __shared__ _Float16 Bl[2][8][512];   // V dbuf
    __shared__ float cbuf[2048];         // per-k correction

    const int f   = blockIdx.x;              // 0..511
    const int xcd = f & 7;
    const int c   = (f >> 3) & 31;           // CU within XCD (assumed)
    const int p   = f >> 8;                  // resident slot (assumed, 0..1)
    const int b   = xcd >> 1;                // batch 0..3
    const int bx  = c & 7;
    const int base = ((xcd & 1) << 3) + ((c >> 3) << 1);   // 0,2,..,14
    const int by  = p ? (15 - base) : base;
    const int d0 = bx * 128;
    const int q0 = by * 128;
    const _Float16* Pb = Pp + (size_t)b * Tt * Tt;
    const float* Pmb = Pm + ((size_t)b * NCH + by) * Tt;
    const float* Mp = Mb + (size_t)b * Tt;
    const float* Lp = Lb + (size_t)b * Tt;
    const _Float16* Vb = Vt + (size_t)b * Dd * Tt;
    float* Ob = Out + (size_t)b * Tt * Dd;

    const int tid = threadIdx.x;
    const int w = tid >> 6, lane = tid & 63;
    const int lr = lane & 15, lq = lane >> 4;
    const int wr = (w >> 1) * 4, wc = (w & 1) * 4;
    const int kmax = q0 + 128;
    const int nstep = kmax >> 5;             // 4*(by+1): even, >= 4

    // precompute c[k] (one pass, cooperative)
    for (int k = tid; k < kmax; k += 256)
        cbuf[k] = __expf(Pmb[k] - Mp[k]) * Lp[k];

    f32x4 acc[4][4];
#pragma unroll
    for (int i = 0; i < 4; ++i)
#pragma unroll
        for (int j = 0; j < 4; ++j)
#pragma unroll
            for (int c2 = 0; c2 < 4; ++c2) acc[i][j][c2] = 0.f;

    half8 RpA[2], RpB[2];
    auto loadP = [&](half8 (&R)[2], int k0) {
#pragma unroll
        for (int s2 = 0; s2 < 2; ++s2) {
            const int s = w * 2 + s2;
            R[s2] = *(const half8*)(Pb + (size_t)(q0 + s * 16 + lr) * Tt + k0 + lq * 8);
        }
    };
    auto issueV = [&](int bf, int k0) {
#pragma unroll
        for (int s2 = 0; s2 < 2; ++s2) {
            const int s = w * 2 + s2;
            GLD16(Vb + (size_t)(d0 + s * 16 + lr) * Tt + k0 + lq * 8, &Bl[bf][s][0]);
        }
    };
    auto writeA = [&](int bf, half8 (&R)[2], int k0) {
        const float* cp = cbuf + k0 + lq * 8;
        float cv[8];
#pragma unroll
        for (int e = 0; e < 8; ++e) cv[e] = cp[e];
#pragma unroll
        for (int s2 = 0; s2 < 2; ++s2) {
            const int s = w * 2 + s2;
            half8 out;
#pragma unroll
            for (int e = 0; e < 8; ++e) out[e] = f2h((float)R[s2][e] * cv[e]);
            *(half8*)&As[bf][s][lane * 8] = out;
        }
    };
    auto domfma = [&](int bf) {
        half8 a[4], b2[4];
#pragma unroll
        for (int i = 0; i < 4; ++i) a[i] = *(const half8*)&As[bf][wr + i][lane * 8];
#pragma unroll
        for (int j = 0; j < 4; ++j) b2[j] = *(const half8*)&Bl[bf][wc + j][lane * 8];
#pragma unroll
        for (int i = 0; i < 4; ++i)
#pragma unroll
            for (int j = 0; j < 4; ++j)
                acc[i][j] = __builtin_amdgcn_mfma_f32_16x16x32_f16(a[i], b2[j], acc[i][j], 0, 0, 0);
    };

    __syncthreads();          // cbuf ready

    // prologue: V(0)->Bl0, P(0)->RpA, P(1)->RpB; build As0
    issueV(0, 0);
    loadP(RpA, 0);
    loadP(RpB, 32);
    WAIT_VM(2);               // V(0)+RpA landed (RpB still flying)
    writeA(0, RpA, 0);
    WAIT_LGKM0();
    BARRIER();

    for (int i = 0; i < nstep; i += 2) {
        // ---- even step i: compute buf0; build buf1 from RpB; prefetch P(i+2)->RpA
        {
            const bool pfP = (i + 2 < nstep);
            issueV(1, (i + 1) << 5);
            if (pfP) loadP(RpA, (i + 2) << 5);
            domfma(0);
            if (pfP) WAIT_VM(4); else WAIT_VM(2);   // RpB landed
            writeA(1, RpB, (i + 1) << 5);
            if (pfP) WAIT_VM(2); else WAIT_VM(0);   // V(i+1) landed (RpA may fly)
            WAIT_LGKM0();                            // my As writes visible
            BARRIER();
        }
        // ---- odd step i+1: compute buf1; build buf0 from RpA; prefetch P(i+3)->RpB
        {
            const bool pfV = (i + 2 < nstep);
            const bool pfP = (i + 3 < nstep);
            if (pfV) issueV(0, (i + 2) << 5);
            if (pfP) loadP(RpB, (i + 3) << 5);
            domfma(1);
            if (pfV) {
                if (pfP) WAIT_VM(4); else WAIT_VM(2);   // RpA landed
                writeA(0, RpA, (i + 2) << 5);
                if (pfP) WAIT_VM(2); else WAIT_VM(0);   // V(i+2) landed
                WAIT_LGKM0();
            }
            BARRIER();
        }
    }

#pragma unroll
    for (int i = 0; i < 4; ++i)
#pragma unroll
        for (int r2 = 0; r2 < 4; ++r2) {
            const int row = q0 + (wr + i) * 16 + lq * 4 + r2;
#pragma unroll
            for (int j = 0; j < 4; ++j)
                Ob[(size_t)row * Dd + d0 + (wc + j) * 16 + lr] = acc[i][j][r2];
        }
}

}  // namespace

extern "C" void kernel_launch(void* const* d_in, const int* in_sizes, int n_in,
                              void* d_out, int out_size, void* d_ws, size_t ws_size,
                              hipStream_t stream)
{
    const float* X  = (const float*)d_in[0];
    const float* Wq = (const float*)d_in[1];
    const float* Wk = (const float*)d_in[2];
    const float* Wv = (const float*)d_in[3];

    char* ws = (char*)d_ws;
    const size_t MB = 1024 * 1024;
    _Float16* Xhi  = (_Float16*)ws;
    _Float16* Xlo  = (_Float16*)(ws + 16 * MB);
    _Float16* Wqh  = (_Float16*)(ws + 32 * MB);
    _Float16* Wql  = (_Float16*)(ws + 34 * MB);
    _Float16* Wkh  = (_Float16*)(ws + 36 * MB);
    _Float16* Wkl  = (_Float16*)(ws + 38 * MB);
    _Float16* WvTh = (_Float16*)(ws + 40 * MB);
    _Float16* GTh  = (_Float16*)(ws + 44 * MB);
    _Float16* GTl  = (_Float16*)(ws + 46 * MB);
    _Float16* Thi  = (_Float16*)(ws + 48 * MB);
    _Float16* Tlo  = (_Float16*)(ws + 64 * MB);
    _Float16* Vt   = (_Float16*)(ws + 80 * MB);
    _Float16* Pp   = (_Float16*)(ws + 112 * MB);      // 32 MB f16 P'
    float*    Mb   = (float*)(ws + 176 * MB);
    float*    Lb   = Mb + (size_t)Bb * Tt;
    float*    Pm   = Lb + (size_t)Bb * Tt;
    float*    Pl   = Pm + (size_t)Bb * NCH * Tt;
    float*    Out  = (float*)d_out;

    convert_all_kernel<<<10496, 256, 0, stream>>>(X, Wq, Wk, Wv, Xhi, Xlo,
                                                  Wqh, Wql, Wkh, Wkl, WvTh);
    gt_kernel<<<dim3(16, 16), 256, 0, stream>>>(Wkh, Wkl, Wqh, Wql, GTh, GTl);
    tv_kernel<<<dim3(1024), 512, 0, stream>>>(Xhi, Xlo, GTh, GTl, WvTh, Thi, Tlo, Vt);
    scores_mfma_kernel<<<dim3(544), 512, 0, stream>>>(Thi, Tlo, Xhi, Xlo, Pp, Pm, Pl);
    colstats_merge_kernel<<<dim3(Tt / 256, Bb), 256, 0, stream>>>(Pm, Pl, Mb, Lb);
    context_mfma_kernel<<<dim3(512), 256, 0, stream>>>(Pp, Pm, Mb, Lb, Vt, Out);
}